// Round 5
// baseline (242.637 us; speedup 1.0000x reference)
//
#include <hip/hip_runtime.h>
#include <hip/hip_bf16.h>
#include <cmath>
#include <cstdint>

// Problem dims (fixed by the reference)
#define BB 4
#define SS 2048
#define DD 1024
#define HH 16
#define MM (BB * SS)   // 8192 tokens

// softmax scale folded into Q weight columns: (1/sqrt(64)) * log2(e)
#define ATT_C 0.18033688011112042f

typedef __attribute__((ext_vector_type(8))) __bf16 bf16x8;
typedef __attribute__((ext_vector_type(4))) float f32x4;
typedef __attribute__((ext_vector_type(8))) float f32x8;
typedef __attribute__((ext_vector_type(8))) unsigned short u16x8;
typedef __attribute__((ext_vector_type(2))) unsigned int u32x2;
typedef __attribute__((ext_vector_type(4))) unsigned int u32x4;

typedef const __attribute__((address_space(3))) unsigned short* lds_cp;

__device__ __forceinline__ unsigned short f2bu(float f) {
  __hip_bfloat16 h = __float2bfloat16(f);
  return __builtin_bit_cast(unsigned short, h);
}

__device__ __forceinline__ f32x4 mfma16(bf16x8 a, bf16x8 b, f32x4 c) {
  return __builtin_amdgcn_mfma_f32_16x16x32_bf16(a, b, c, 0, 0, 0);
}

#define GLD16(gp, lp) __builtin_amdgcn_global_load_lds(                     \
    (const __attribute__((address_space(1))) void*)(gp),                    \
    (__attribute__((address_space(3))) void*)(lp), 16, 0, 0)

// ---------------- prep: fp32 -> bf16 cast (vectorized) ----------------
__global__ __launch_bounds__(256) void k_cast_bf16(const float* __restrict__ in,
                                                   unsigned short* __restrict__ out,
                                                   int n) {
  int i = (blockIdx.x * 256 + threadIdx.x) * 8;
  if (i >= n) return;
  f32x8 v = *(const f32x8*)(in + i);
  u16x8 o;
#pragma unroll
  for (int j = 0; j < 8; ++j) o[j] = f2bu(v[j]);
  *(u16x8*)(out + i) = o;
}

// ---------------- prep: transpose + cast  in[R][C] f32 -> out[C][R] bf16 ----------------
// output rows < scale_end get multiplied by scale (folds softmax scale into Q weights)
__global__ __launch_bounds__(256) void k_transpose_bf16(const float* __restrict__ in,
                                                        unsigned short* __restrict__ out,
                                                        int R, int C,
                                                        float scale, int scale_end) {
  __shared__ float tile[32][33];
  const int c0 = blockIdx.x * 32, r0 = blockIdx.y * 32;
  const int tx = threadIdx.x & 31, ty = threadIdx.x >> 5;  // ty 0..7
#pragma unroll
  for (int i = ty; i < 32; i += 8)
    tile[i][tx] = in[(size_t)(r0 + i) * C + c0 + tx];
  __syncthreads();
#pragma unroll
  for (int i = ty; i < 32; i += 8) {
    float v = tile[tx][i];
    if (c0 + i < scale_end) v *= scale;
    out[(size_t)(c0 + i) * R + r0 + tx] = f2bu(v);
  }
}

// ---------------- bf16 GEMM, m97 structure ----------------
// C[M][N] = A[M][K] * Bt[N][K]^T + bias[N]  (bias cols < bias_scale_end scaled by ATT_C)
template <int OUT_F32>
__global__ __launch_bounds__(256) void k_gemm_bt(const unsigned short* __restrict__ A,
                                                 const unsigned short* __restrict__ Bt,
                                                 const float* __restrict__ bias,
                                                 void* __restrict__ Cout,
                                                 int M, int N, int K, int bias_scale_end) {
  __shared__ __attribute__((aligned(16))) unsigned short lA[128 * 64];
  __shared__ __attribute__((aligned(16))) unsigned short lB[128 * 64];
  const int tid = threadIdx.x;
  const int wave = tid >> 6, lane = tid & 63;
  const int g = lane >> 4, c = lane & 15;
  const int wr = wave >> 1, wc = wave & 1;
  const int m0 = blockIdx.y * 128, n0 = blockIdx.x * 128;
  const int srow = lane >> 3, scol = (lane & 7) * 8;

  f32x4 acc[4][4] = {};

  for (int k0 = 0; k0 < K; k0 += 64) {
#pragma unroll
    for (int i = 0; i < 4; ++i) {
      const int chunk = i * 4 + wave;  // wave-uniform
      GLD16(A + (size_t)(m0 + chunk * 8 + srow) * K + k0 + scol, lA + chunk * 512);
      GLD16(Bt + (size_t)(n0 + chunk * 8 + srow) * K + k0 + scol, lB + chunk * 512);
    }
    __syncthreads();
#pragma unroll
    for (int kk = 0; kk < 2; ++kk) {
      bf16x8 af[4], bfr[4];
#pragma unroll
      for (int mi = 0; mi < 4; ++mi)
        af[mi] = *(const bf16x8*)&lA[(wr * 64 + mi * 16 + c) * 64 + kk * 32 + g * 8];
#pragma unroll
      for (int ni = 0; ni < 4; ++ni)
        bfr[ni] = *(const bf16x8*)&lB[(wc * 64 + ni * 16 + c) * 64 + kk * 32 + g * 8];
#pragma unroll
      for (int mi = 0; mi < 4; ++mi)
#pragma unroll
        for (int ni = 0; ni < 4; ++ni)
          acc[mi][ni] = mfma16(af[mi], bfr[ni], acc[mi][ni]);
    }
    __syncthreads();
  }

#pragma unroll
  for (int mi = 0; mi < 4; ++mi)
#pragma unroll
    for (int ni = 0; ni < 4; ++ni) {
      const int col = n0 + wc * 64 + ni * 16 + c;
      float bv = bias[col];
      if (col < bias_scale_end) bv *= ATT_C;
#pragma unroll
      for (int r = 0; r < 4; ++r) {
        const int row = m0 + wr * 64 + mi * 16 + g * 4 + r;
        const float v = acc[mi][ni][r] + bv;
        if (OUT_F32)
          ((float*)Cout)[(size_t)row * N + col] = v;
        else
          ((unsigned short*)Cout)[(size_t)row * N + col] = f2bu(v);
      }
    }
}

// ---------------- causal flash attention (swapped QK^T, tr-read PV) ----------------
// qkv: [B*S][3072] bf16 (Q at 0 pre-scaled by ATT_C, K at 1024, V at 2048; head h at h*64)
// y:   [B*S][1024] bf16
// Block: 4 waves x 32 Q rows = 128-row q-tile, ONE q-tile per block (longest-first,
// all 1024 blocks co-resident -> ~16 waves/CU). KVBLK=64, dbuf LDS.
// K LDS: row-major [64 keys][64 hd], 16B-chunk XOR swizzle ch^(row&7); staged coalesced.
// V LDS: tr-subtiles ordered (k4*4+dc)*128B -> staging is 8 contiguous rows per GLD16
//   (coalesced); tr-read uses group-strided base (lane>>4)*512B + (lane&15)*8B.
// Row-sums of P computed via ones-MFMA (lands in o's register layout; no shfl).
__global__ __launch_bounds__(256) void k_attn(const unsigned short* __restrict__ qkv,
                                              unsigned short* __restrict__ y) {
  __shared__ __attribute__((aligned(16))) unsigned short lK[2][4096];
  __shared__ __attribute__((aligned(16))) unsigned short lV[2][4096];

  const int tid = threadIdx.x, wave = tid >> 6, lane = tid & 63;
  const int g = lane >> 4, c = lane & 15;
  const int bh = blockIdx.y, b = bh >> 4, hc = bh & 15;
  const size_t rb = (size_t)b * SS;

  // staging lane constants
  const int kRow = lane >> 3;                                  // 0..7 row within group
  const int kCh  = ((lane & 7) ^ kRow) * 8;                    // XOR-swizzled dim chunk
  const int vRow = 4 * ((lane >> 5) & 1) + ((lane >> 1) & 3);  // 0..7 key within group
  const int vDim = 16 * ((lane >> 3) & 3) + (lane & 1) * 8;    // dim offset

#define STAGE(buf, kb) do {                                                        \
    const int k0s = (kb) * 64;                                                     \
    const int g16 = wave * 16;                                                     \
    GLD16(qkv + (rb + k0s + g16 + kRow) * 3072 + 1024 + hc * 64 + kCh,             \
          &lK[buf][0] + g16 * 64);                                                 \
    GLD16(qkv + (rb + k0s + g16 + 8 + kRow) * 3072 + 1024 + hc * 64 + kCh,         \
          &lK[buf][0] + (g16 + 8) * 64);                                           \
    GLD16(qkv + (rb + k0s + g16 + vRow) * 3072 + 2048 + hc * 64 + vDim,            \
          &lV[buf][0] + g16 * 64);                                                 \
    GLD16(qkv + (rb + k0s + g16 + 8 + vRow) * 3072 + 2048 + hc * 64 + vDim,        \
          &lV[buf][0] + (g16 + 8) * 64);                                           \
  } while (0)

#define TRRD(dst, OFFLIT) \
  asm volatile("ds_read_b64_tr_b16 %0, %1 offset:" OFFLIT : "=v"(dst) : "v"(vp))
#define DSR128(dst, ptr, OFFLIT) \
  asm volatile("ds_read_b128 %0, %1 offset:" OFFLIT : "=v"(dst) : "v"(ptr))
#define LGKM(N) do { asm volatile("s_waitcnt lgkmcnt(" #N ")" ::: "memory"); \
                     __builtin_amdgcn_sched_barrier(0); } while (0)

  const int qt = 15 - (int)blockIdx.x;  // longest blocks first
  const int qw = qt * 128 + wave * 32;  // wave's first q row

  // Q B-frags (scale pre-folded into weights): B[col=q=c][k=hd]
  bf16x8 qf[2][2];
#pragma unroll
  for (int m = 0; m < 2; ++m)
#pragma unroll
    for (int kh = 0; kh < 2; ++kh)
      qf[m][kh] = *(const bf16x8*)(qkv + (rb + qw + m * 16 + c) * 3072 + hc * 64 + kh * 32 + g * 8);

  // all-ones B-frag for row-sum MFMA
  bf16x8 onesf;
  {
    u16x8 t;
#pragma unroll
    for (int j = 0; j < 8; ++j) t[j] = 0x3F80;  // bf16 1.0
    onesf = __builtin_bit_cast(bf16x8, t);
  }

  float mrun[2] = {-INFINITY, -INFINITY};
  f32x4 lsum[2] = {};
  f32x4 o[2][4] = {};
  const int nkb = 2 * qt + 2;

  auto compute = [&](int buf, int kb) {
    const int k0 = kb * 64;
    if (k0 > qw + 31) return;  // fully masked for this wave (wave-uniform)

    // --- K fragments: swizzled b128 reads + issue V tr-reads (kh=0) ---
    const lds_cp kbase = (lds_cp)&lK[buf][0];
    const lds_cp kp0 = kbase + c * 64 + ((g ^ (c & 7))) * 8;
    const lds_cp kp1 = kbase + c * 64 + (((4 + g) ^ (c & 7))) * 8;
    u32x4 kr[8];
    DSR128(kr[0], kp0, "0");    DSR128(kr[1], kp0, "2048");
    DSR128(kr[2], kp0, "4096"); DSR128(kr[3], kp0, "6144");
    DSR128(kr[4], kp1, "0");    DSR128(kr[5], kp1, "2048");
    DSR128(kr[6], kp1, "4096"); DSR128(kr[7], kp1, "6144");
    const lds_cp vp = (lds_cp)&lV[buf][0] + (lane >> 4) * 256 + (lane & 15) * 4;
    u32x2 t0[8];  // [2*dc + jh] : subtile (k4 = 4*jh + g, dc)
    TRRD(t0[0], "0");   TRRD(t0[1], "2048");
    TRRD(t0[2], "128"); TRRD(t0[3], "2176");
    TRRD(t0[4], "256"); TRRD(t0[5], "2304");
    TRRD(t0[6], "384"); TRRD(t0[7], "2432");
    LGKM(8);  // kr ready (t0 still in flight)

    // --- S^T = mfma(K, Q): D[key=4g+r (+16kf)][q=c (+16m)] ---
    f32x4 s[2][4];
    __builtin_amdgcn_s_setprio(1);
#pragma unroll
    for (int kf = 0; kf < 4; ++kf) {
      const bf16x8 ka = __builtin_bit_cast(bf16x8, kr[kf]);
      const bf16x8 kb2 = __builtin_bit_cast(bf16x8, kr[4 + kf]);
#pragma unroll
      for (int m = 0; m < 2; ++m) {
        f32x4 a = {};
        a = mfma16(ka, qf[m][0], a);
        a = mfma16(kb2, qf[m][1], a);
        s[m][kf] = a;
      }
    }
    __builtin_amdgcn_s_setprio(0);

    // --- issue V tr-reads for kh=1 (land under softmax/PV0) ---
    u32x2 t1[8];
    TRRD(t1[0], "4096"); TRRD(t1[1], "6144");
    TRRD(t1[2], "4224"); TRRD(t1[3], "6272");
    TRRD(t1[4], "4352"); TRRD(t1[5], "6400");
    TRRD(t1[6], "4480"); TRRD(t1[7], "6528");

    // --- causal mask (diagonal-touching frags only) ---
#pragma unroll
    for (int m = 0; m < 2; ++m)
#pragma unroll
      for (int kf = 0; kf < 4; ++kf)
        if (k0 + kf * 16 + 15 > qw + m * 16) {
#pragma unroll
          for (int r = 0; r < 4; ++r)
            if (k0 + kf * 16 + 4 * g + r > qw + m * 16 + c) s[m][kf][r] = -INFINITY;
        }

    // --- online softmax (log2 domain; max3 trees; defer-max) ---
#pragma unroll
    for (int m = 0; m < 2; ++m) {
      // 16 -> max3-shaped reduction (8 ops)
      float a0 = fmaxf(fmaxf(s[m][0][0], s[m][0][1]), s[m][0][2]);
      float a1 = fmaxf(fmaxf(s[m][0][3], s[m][1][0]), s[m][1][1]);
      float a2 = fmaxf(fmaxf(s[m][1][2], s[m][1][3]), s[m][2][0]);
      float a3 = fmaxf(fmaxf(s[m][2][1], s[m][2][2]), s[m][2][3]);
      float a4 = fmaxf(fmaxf(s[m][3][0], s[m][3][1]), s[m][3][2]);
      float b0 = fmaxf(fmaxf(a0, a1), a2);
      float b1 = fmaxf(fmaxf(a3, a4), s[m][3][3]);
      float tmax = fmaxf(b0, b1);
      tmax = fmaxf(tmax, __shfl_xor(tmax, 16));
      tmax = fmaxf(tmax, __shfl_xor(tmax, 32));
      const float mold = mrun[m];
      float mt;
      if (__all(tmax - mold <= 8.f)) {
        mt = mold;
      } else {
        mt = fmaxf(mold, tmax);
        const float alpha = __builtin_amdgcn_exp2f(mold - mt);
        mrun[m] = mt;
#pragma unroll
        for (int r = 0; r < 4; ++r) {
          const float ao = __shfl(alpha, (lane & 48) + ((lane & 48) >> 2) + r);
          lsum[m][r] *= ao;
#pragma unroll
          for (int dc = 0; dc < 4; ++dc) o[m][dc][r] *= ao;
        }
      }
#pragma unroll
      for (int kf = 0; kf < 4; ++kf)
#pragma unroll
        for (int r = 0; r < 4; ++r)
          s[m][kf][r] = __builtin_amdgcn_exp2f(s[m][kf][r] - mt);
    }

    // --- pack P -> bf16 A-frags ---
    bf16x8 pa[2][2];
#pragma unroll
    for (int m = 0; m < 2; ++m)
#pragma unroll
      for (int kh = 0; kh < 2; ++kh) {
        u16x8 t;
#pragma unroll
        for (int j = 0; j < 4; ++j) {
          t[j]     = f2bu(s[m][2 * kh][j]);
          t[4 + j] = f2bu(s[m][2 * kh + 1][j]);
        }
        pa[m][kh] = __builtin_bit_cast(bf16x8, t);
      }

    LGKM(8);  // t0 ready (t1 younger, still allowed in flight)
    __builtin_amdgcn_s_setprio(1);
    // row-sums via ones-MFMA (joins the MFMA cluster; replaces fadd tree + shfls)
#pragma unroll
    for (int m = 0; m < 2; ++m) {
      lsum[m] = mfma16(pa[m][0], onesf, lsum[m]);
      lsum[m] = mfma16(pa[m][1], onesf, lsum[m]);
    }
#pragma unroll
    for (int dc = 0; dc < 4; ++dc) {
      u32x4 vv = {t0[2 * dc][0], t0[2 * dc][1], t0[2 * dc + 1][0], t0[2 * dc + 1][1]};
      const bf16x8 vf = __builtin_bit_cast(bf16x8, vv);
#pragma unroll
      for (int m = 0; m < 2; ++m) o[m][dc] = mfma16(pa[m][0], vf, o[m][dc]);
    }
    __builtin_amdgcn_s_setprio(0);

    LGKM(0);  // t1 ready
    __builtin_amdgcn_s_setprio(1);
#pragma unroll
    for (int dc = 0; dc < 4; ++dc) {
      u32x4 vv = {t1[2 * dc][0], t1[2 * dc][1], t1[2 * dc + 1][0], t1[2 * dc + 1][1]};
      const bf16x8 vf = __builtin_bit_cast(bf16x8, vv);
#pragma unroll
      for (int m = 0; m < 2; ++m) o[m][dc] = mfma16(pa[m][1], vf, o[m][dc]);
    }
    __builtin_amdgcn_s_setprio(0);
  };

  STAGE(0, 0);
  asm volatile("s_waitcnt vmcnt(0)" ::: "memory");
  __syncthreads();
  int cur = 0;
  for (int kb = 0; kb < nkb - 1; ++kb) {
    STAGE(cur ^ 1, kb + 1);
    compute(cur, kb);
    asm volatile("s_waitcnt vmcnt(0)" ::: "memory");
    __syncthreads();
    cur ^= 1;
  }
  compute(cur, nkb - 1);

  // epilogue: normalize and store (lsum already in o's layout — no shfl)
#pragma unroll
  for (int m = 0; m < 2; ++m)
#pragma unroll
    for (int r = 0; r < 4; ++r) {
      const float inv = __builtin_amdgcn_rcpf(lsum[m][r]);
      const int q = qw + m * 16 + 4 * g + r;
#pragma unroll
      for (int dc = 0; dc < 4; ++dc)
        y[(rb + q) * 1024 + hc * 64 + dc * 16 + c] = f2bu(o[m][dc][r] * inv);
    }
#undef STAGE
#undef TRRD
#undef DSR128
#undef LGKM
}

// ---------------- launch ----------------
extern "C" void kernel_launch(void* const* d_in, const int* in_sizes, int n_in,
                              void* d_out, int out_size, void* d_ws, size_t ws_size,
                              hipStream_t stream) {
  (void)in_sizes; (void)n_in; (void)out_size; (void)ws_size;
  const float* x     = (const float*)d_in[0];
  const float* w_qkv = (const float*)d_in[1];
  const float* b_qkv = (const float*)d_in[2];
  const float* w_out = (const float*)d_in[3];
  const float* b_out = (const float*)d_in[4];
  float* out = (float*)d_out;

  char* ws = (char*)d_ws;
  unsigned short* x_bf  = (unsigned short*)(ws);                        // 16 MB (reused for y)
  unsigned short* wqkvT = (unsigned short*)(ws + (size_t)16 * 1048576); // 6 MB
  unsigned short* woutT = (unsigned short*)(ws + (size_t)22 * 1048576); // 2 MB
  unsigned short* qkv   = (unsigned short*)(ws + (size_t)24 * 1048576); // 48 MB -> total 72 MB

  // prep (Q weight columns pre-scaled by ATT_C)
  k_cast_bf16<<<dim3((MM * DD) / (256 * 8)), 256, 0, stream>>>(x, x_bf, MM * DD);
  k_transpose_bf16<<<dim3(3 * DD / 32, DD / 32), 256, 0, stream>>>(w_qkv, wqkvT, DD, 3 * DD,
                                                                   ATT_C, DD);
  k_transpose_bf16<<<dim3(DD / 32, DD / 32), 256, 0, stream>>>(w_out, woutT, DD, DD, 1.f, 0);

  // QKV projection: [8192,3072] bf16
  k_gemm_bt<0><<<dim3(3 * DD / 128, MM / 128), 256, 0, stream>>>(
      x_bf, wqkvT, b_qkv, qkv, MM, 3 * DD, DD, DD);

  // causal attention -> y (bf16, reuses x_bf region)
  k_attn<<<dim3(16, BB * HH), 256, 0, stream>>>(qkv, x_bf);

  // output projection: fp32 out
  k_gemm_bt<1><<<dim3(DD / 128, MM / 128), 256, 0, stream>>>(
      x_bf, woutT, b_out, out, MM, DD, DD, 0);
}

// Round 6
// 212.369 us; speedup vs baseline: 1.1425x; 1.1425x over previous
//
#include <hip/hip_runtime.h>
#include <hip/hip_bf16.h>
#include <cmath>
#include <cstdint>

// Problem dims (fixed by the reference)
#define BB 4
#define SS 2048
#define DD 1024
#define HH 16
#define MM (BB * SS)   // 8192 tokens

// softmax scale folded into Q weight columns: (1/sqrt(64)) * log2(e)
#define ATT_C 0.18033688011112042f

typedef __attribute__((ext_vector_type(8))) __bf16 bf16x8;
typedef __attribute__((ext_vector_type(4))) float f32x4;
typedef __attribute__((ext_vector_type(8))) float f32x8;
typedef __attribute__((ext_vector_type(8))) unsigned short u16x8;
typedef __attribute__((ext_vector_type(2))) unsigned int u32x2;
typedef __attribute__((ext_vector_type(4))) unsigned int u32x4;

typedef const __attribute__((address_space(3))) unsigned short* lds_cp;

__device__ __forceinline__ unsigned short f2bu(float f) {
  __hip_bfloat16 h = __float2bfloat16(f);
  return __builtin_bit_cast(unsigned short, h);
}

__device__ __forceinline__ f32x4 mfma16(bf16x8 a, bf16x8 b, f32x4 c) {
  return __builtin_amdgcn_mfma_f32_16x16x32_bf16(a, b, c, 0, 0, 0);
}

#define GLD16(gp, lp) __builtin_amdgcn_global_load_lds(                     \
    (const __attribute__((address_space(1))) void*)(gp),                    \
    (__attribute__((address_space(3))) void*)(lp), 16, 0, 0)

// ---------------- prep: fp32 -> bf16 cast (vectorized) ----------------
__global__ __launch_bounds__(256) void k_cast_bf16(const float* __restrict__ in,
                                                   unsigned short* __restrict__ out,
                                                   int n) {
  int i = (blockIdx.x * 256 + threadIdx.x) * 8;
  if (i >= n) return;
  f32x8 v = *(const f32x8*)(in + i);
  u16x8 o;
#pragma unroll
  for (int j = 0; j < 8; ++j) o[j] = f2bu(v[j]);
  *(u16x8*)(out + i) = o;
}

// ---------------- prep: transpose + cast  in[R][C] f32 -> out[C][R] bf16 ----------------
// output rows < scale_end get multiplied by scale (folds softmax scale into Q weights)
__global__ __launch_bounds__(256) void k_transpose_bf16(const float* __restrict__ in,
                                                        unsigned short* __restrict__ out,
                                                        int R, int C,
                                                        float scale, int scale_end) {
  __shared__ float tile[32][33];
  const int c0 = blockIdx.x * 32, r0 = blockIdx.y * 32;
  const int tx = threadIdx.x & 31, ty = threadIdx.x >> 5;  // ty 0..7
#pragma unroll
  for (int i = ty; i < 32; i += 8)
    tile[i][tx] = in[(size_t)(r0 + i) * C + c0 + tx];
  __syncthreads();
#pragma unroll
  for (int i = ty; i < 32; i += 8) {
    float v = tile[tx][i];
    if (c0 + i < scale_end) v *= scale;
    out[(size_t)(c0 + i) * R + r0 + tx] = f2bu(v);
  }
}

// ---------------- bf16 GEMM, m97 structure ----------------
// C[M][N] = A[M][K] * Bt[N][K]^T + bias[N]  (bias cols < bias_scale_end scaled by ATT_C)
template <int OUT_F32>
__global__ __launch_bounds__(256) void k_gemm_bt(const unsigned short* __restrict__ A,
                                                 const unsigned short* __restrict__ Bt,
                                                 const float* __restrict__ bias,
                                                 void* __restrict__ Cout,
                                                 int M, int N, int K, int bias_scale_end) {
  __shared__ __attribute__((aligned(16))) unsigned short lA[128 * 64];
  __shared__ __attribute__((aligned(16))) unsigned short lB[128 * 64];
  const int tid = threadIdx.x;
  const int wave = tid >> 6, lane = tid & 63;
  const int g = lane >> 4, c = lane & 15;
  const int wr = wave >> 1, wc = wave & 1;
  const int m0 = blockIdx.y * 128, n0 = blockIdx.x * 128;
  const int srow = lane >> 3, scol = (lane & 7) * 8;

  f32x4 acc[4][4] = {};

  for (int k0 = 0; k0 < K; k0 += 64) {
#pragma unroll
    for (int i = 0; i < 4; ++i) {
      const int chunk = i * 4 + wave;  // wave-uniform
      GLD16(A + (size_t)(m0 + chunk * 8 + srow) * K + k0 + scol, lA + chunk * 512);
      GLD16(Bt + (size_t)(n0 + chunk * 8 + srow) * K + k0 + scol, lB + chunk * 512);
    }
    __syncthreads();
#pragma unroll
    for (int kk = 0; kk < 2; ++kk) {
      bf16x8 af[4], bfr[4];
#pragma unroll
      for (int mi = 0; mi < 4; ++mi)
        af[mi] = *(const bf16x8*)&lA[(wr * 64 + mi * 16 + c) * 64 + kk * 32 + g * 8];
#pragma unroll
      for (int ni = 0; ni < 4; ++ni)
        bfr[ni] = *(const bf16x8*)&lB[(wc * 64 + ni * 16 + c) * 64 + kk * 32 + g * 8];
#pragma unroll
      for (int mi = 0; mi < 4; ++mi)
#pragma unroll
        for (int ni = 0; ni < 4; ++ni)
          acc[mi][ni] = mfma16(af[mi], bfr[ni], acc[mi][ni]);
    }
    __syncthreads();
  }

#pragma unroll
  for (int mi = 0; mi < 4; ++mi)
#pragma unroll
    for (int ni = 0; ni < 4; ++ni) {
      const int col = n0 + wc * 64 + ni * 16 + c;
      float bv = bias[col];
      if (col < bias_scale_end) bv *= ATT_C;
#pragma unroll
      for (int r = 0; r < 4; ++r) {
        const int row = m0 + wr * 64 + mi * 16 + g * 4 + r;
        const float v = acc[mi][ni][r] + bv;
        if (OUT_F32)
          ((float*)Cout)[(size_t)row * N + col] = v;
        else
          ((unsigned short*)Cout)[(size_t)row * N + col] = f2bu(v);
      }
    }
}

// ---------------- causal flash attention (swapped QK^T, tr-read PV) ----------------
// qkv: [B*S][3072] bf16 (Q at 0 pre-scaled by ATT_C, K at 1024, V at 2048; head h at h*64)
// y:   [B*S][1024] bf16
// Block: 4 waves x 16 Q rows = 64-row q-tile; each block runs TWO q-tiles (31-x, x)
// sequentially -> uniform 33 tile-steps. Grid 16x64 = 1024 blocks (~4/CU, 16 waves/CU).
// KVBLK=64, dbuf LDS.
// K LDS: row-major [64 keys][64 hd], 16B-chunk XOR swizzle ch^(row&7); staged coalesced.
// V LDS: tr-subtiles ordered (k4*4+dc)*128B -> staging is 8 contiguous rows per GLD16
//   (coalesced); tr-read uses group-strided base (lane>>4)*512B + (lane&15)*8B.
// Row-sums of P via ones-MFMA (lands in o's register layout; no shfl).
__global__ __launch_bounds__(256) void k_attn(const unsigned short* __restrict__ qkv,
                                              unsigned short* __restrict__ y) {
  __shared__ __attribute__((aligned(16))) unsigned short lK[2][4096];
  __shared__ __attribute__((aligned(16))) unsigned short lV[2][4096];

  const int tid = threadIdx.x, wave = tid >> 6, lane = tid & 63;
  const int g = lane >> 4, c = lane & 15;
  const int bh = blockIdx.y, b = bh >> 4, hc = bh & 15;
  const size_t rb = (size_t)b * SS;

  // staging lane constants
  const int kRow = lane >> 3;                                  // 0..7 row within group
  const int kCh  = ((lane & 7) ^ kRow) * 8;                    // XOR-swizzled dim chunk
  const int vRow = 4 * ((lane >> 5) & 1) + ((lane >> 1) & 3);  // 0..7 key within group
  const int vDim = 16 * ((lane >> 3) & 3) + (lane & 1) * 8;    // dim offset

#define STAGE(buf, kb) do {                                                        \
    const int k0s = (kb) * 64;                                                     \
    const int g16 = wave * 16;                                                     \
    GLD16(qkv + (rb + k0s + g16 + kRow) * 3072 + 1024 + hc * 64 + kCh,             \
          &lK[buf][0] + g16 * 64);                                                 \
    GLD16(qkv + (rb + k0s + g16 + 8 + kRow) * 3072 + 1024 + hc * 64 + kCh,         \
          &lK[buf][0] + (g16 + 8) * 64);                                           \
    GLD16(qkv + (rb + k0s + g16 + vRow) * 3072 + 2048 + hc * 64 + vDim,            \
          &lV[buf][0] + g16 * 64);                                                 \
    GLD16(qkv + (rb + k0s + g16 + 8 + vRow) * 3072 + 2048 + hc * 64 + vDim,        \
          &lV[buf][0] + (g16 + 8) * 64);                                           \
  } while (0)

#define TRRD(dst, OFFLIT) \
  asm volatile("ds_read_b64_tr_b16 %0, %1 offset:" OFFLIT : "=v"(dst) : "v"(vp))
#define DSR128(dst, ptr, OFFLIT) \
  asm volatile("ds_read_b128 %0, %1 offset:" OFFLIT : "=v"(dst) : "v"(ptr))
#define LGKM(N) do { asm volatile("s_waitcnt lgkmcnt(" #N ")" ::: "memory"); \
                     __builtin_amdgcn_sched_barrier(0); } while (0)

  // all-ones B-frag for row-sum MFMA
  bf16x8 onesf;
  {
    u16x8 t;
#pragma unroll
    for (int j = 0; j < 8; ++j) t[j] = 0x3F80;  // bf16 1.0
    onesf = __builtin_bit_cast(bf16x8, t);
  }

  auto run_qtile = [&](int qt) {
    const int qw = qt * 64 + wave * 16;  // wave's first q row (16 rows per wave)

    // Q B-frags (scale pre-folded into weights): B[col=q=c][k=hd]
    bf16x8 qf[2];
#pragma unroll
    for (int kh = 0; kh < 2; ++kh)
      qf[kh] = *(const bf16x8*)(qkv + (rb + qw + c) * 3072 + hc * 64 + kh * 32 + g * 8);

    float mrun = -INFINITY;
    f32x4 lsum = {};
    f32x4 o[4] = {};
    const int nkb = qt + 1;

    auto compute = [&](int buf, int kb) {
      const int k0 = kb * 64;
      if (k0 > qw + 15) return;  // fully masked for this wave (wave-uniform)

      // --- K fragments: swizzled b128 reads + issue V tr-reads (kh=0) ---
      const lds_cp kbase = (lds_cp)&lK[buf][0];
      const lds_cp kp0 = kbase + c * 64 + ((g ^ (c & 7))) * 8;
      const lds_cp kp1 = kbase + c * 64 + (((4 + g) ^ (c & 7))) * 8;
      u32x4 kr[8];
      DSR128(kr[0], kp0, "0");    DSR128(kr[1], kp0, "2048");
      DSR128(kr[2], kp0, "4096"); DSR128(kr[3], kp0, "6144");
      DSR128(kr[4], kp1, "0");    DSR128(kr[5], kp1, "2048");
      DSR128(kr[6], kp1, "4096"); DSR128(kr[7], kp1, "6144");
      const lds_cp vp = (lds_cp)&lV[buf][0] + (lane >> 4) * 256 + (lane & 15) * 4;
      u32x2 t0[8];  // [2*dc + jh] : subtile (k4 = 4*jh + g, dc)
      TRRD(t0[0], "0");   TRRD(t0[1], "2048");
      TRRD(t0[2], "128"); TRRD(t0[3], "2176");
      TRRD(t0[4], "256"); TRRD(t0[5], "2304");
      TRRD(t0[6], "384"); TRRD(t0[7], "2432");
      LGKM(8);  // kr ready (t0 still in flight)

      // --- S^T = mfma(K, Q): D[key=4g+r (+16kf)][q=c] ---
      f32x4 s[4];
      __builtin_amdgcn_s_setprio(1);
#pragma unroll
      for (int kf = 0; kf < 4; ++kf) {
        const bf16x8 ka = __builtin_bit_cast(bf16x8, kr[kf]);
        const bf16x8 kb2 = __builtin_bit_cast(bf16x8, kr[4 + kf]);
        f32x4 a = {};
        a = mfma16(ka, qf[0], a);
        a = mfma16(kb2, qf[1], a);
        s[kf] = a;
      }
      __builtin_amdgcn_s_setprio(0);

      // --- issue V tr-reads for kh=1 (land under softmax/PV0) ---
      u32x2 t1[8];
      TRRD(t1[0], "4096"); TRRD(t1[1], "6144");
      TRRD(t1[2], "4224"); TRRD(t1[3], "6272");
      TRRD(t1[4], "4352"); TRRD(t1[5], "6400");
      TRRD(t1[6], "4480"); TRRD(t1[7], "6528");

      // --- causal mask (diagonal-touching frags only) ---
#pragma unroll
      for (int kf = 0; kf < 4; ++kf)
        if (k0 + kf * 16 + 15 > qw) {
#pragma unroll
          for (int r = 0; r < 4; ++r)
            if (k0 + kf * 16 + 4 * g + r > qw + c) s[kf][r] = -INFINITY;
        }

      // --- online softmax (log2 domain; max3 trees; defer-max) ---
      {
        float a0 = fmaxf(fmaxf(s[0][0], s[0][1]), s[0][2]);
        float a1 = fmaxf(fmaxf(s[0][3], s[1][0]), s[1][1]);
        float a2 = fmaxf(fmaxf(s[1][2], s[1][3]), s[2][0]);
        float a3 = fmaxf(fmaxf(s[2][1], s[2][2]), s[2][3]);
        float a4 = fmaxf(fmaxf(s[3][0], s[3][1]), s[3][2]);
        float b0 = fmaxf(fmaxf(a0, a1), a2);
        float b1 = fmaxf(fmaxf(a3, a4), s[3][3]);
        float tmax = fmaxf(b0, b1);
        tmax = fmaxf(tmax, __shfl_xor(tmax, 16));
        tmax = fmaxf(tmax, __shfl_xor(tmax, 32));
        const float mold = mrun;
        float mt;
        if (__all(tmax - mold <= 8.f)) {
          mt = mold;
        } else {
          mt = fmaxf(mold, tmax);
          const float alpha = __builtin_amdgcn_exp2f(mold - mt);
          mrun = mt;
#pragma unroll
          for (int r = 0; r < 4; ++r) {
            const float ao = __shfl(alpha, (lane & 48) + ((lane & 48) >> 2) + r);
            lsum[r] *= ao;
#pragma unroll
            for (int dc = 0; dc < 4; ++dc) o[dc][r] *= ao;
          }
        }
#pragma unroll
        for (int kf = 0; kf < 4; ++kf)
#pragma unroll
          for (int r = 0; r < 4; ++r)
            s[kf][r] = __builtin_amdgcn_exp2f(s[kf][r] - mt);
      }

      // --- pack P -> bf16 A-frags ---
      bf16x8 pa[2];
#pragma unroll
      for (int kh = 0; kh < 2; ++kh) {
        u16x8 t;
#pragma unroll
        for (int j = 0; j < 4; ++j) {
          t[j]     = f2bu(s[2 * kh][j]);
          t[4 + j] = f2bu(s[2 * kh + 1][j]);
        }
        pa[kh] = __builtin_bit_cast(bf16x8, t);
      }

      LGKM(8);  // t0 ready (t1 younger, still allowed in flight)
      __builtin_amdgcn_s_setprio(1);
      // row-sums via ones-MFMA (replaces fadd tree + shfls)
      lsum = mfma16(pa[0], onesf, lsum);
      lsum = mfma16(pa[1], onesf, lsum);
#pragma unroll
      for (int dc = 0; dc < 4; ++dc) {
        u32x4 vv = {t0[2 * dc][0], t0[2 * dc][1], t0[2 * dc + 1][0], t0[2 * dc + 1][1]};
        const bf16x8 vf = __builtin_bit_cast(bf16x8, vv);
        o[dc] = mfma16(pa[0], vf, o[dc]);
      }
      __builtin_amdgcn_s_setprio(0);

      LGKM(0);  // t1 ready
      __builtin_amdgcn_s_setprio(1);
#pragma unroll
      for (int dc = 0; dc < 4; ++dc) {
        u32x4 vv = {t1[2 * dc][0], t1[2 * dc][1], t1[2 * dc + 1][0], t1[2 * dc + 1][1]};
        const bf16x8 vf = __builtin_bit_cast(bf16x8, vv);
        o[dc] = mfma16(pa[1], vf, o[dc]);
      }
      __builtin_amdgcn_s_setprio(0);
    };

    __syncthreads();  // LDS handoff from previous q-tile (no-op cost on first)
    STAGE(0, 0);
    asm volatile("s_waitcnt vmcnt(0)" ::: "memory");
    __syncthreads();
    int cur = 0;
    for (int kb = 0; kb < nkb - 1; ++kb) {
      STAGE(cur ^ 1, kb + 1);
      compute(cur, kb);
      asm volatile("s_waitcnt vmcnt(0)" ::: "memory");
      __syncthreads();
      cur ^= 1;
    }
    compute(cur, nkb - 1);

    // epilogue: normalize and store (lsum already in o's layout — no shfl)
#pragma unroll
    for (int r = 0; r < 4; ++r) {
      const float inv = __builtin_amdgcn_rcpf(lsum[r]);
      const int q = qw + 4 * g + r;
#pragma unroll
      for (int dc = 0; dc < 4; ++dc)
        y[(rb + q) * 1024 + hc * 64 + dc * 16 + c] = f2bu(o[dc][r] * inv);
    }
  };

  // paired q-tiles: (31-x) then (x) -> uniform 33 tile-steps per block
  run_qtile(31 - (int)blockIdx.x);
  run_qtile((int)blockIdx.x);
#undef STAGE
#undef TRRD
#undef DSR128
#undef LGKM
}

// ---------------- launch ----------------
extern "C" void kernel_launch(void* const* d_in, const int* in_sizes, int n_in,
                              void* d_out, int out_size, void* d_ws, size_t ws_size,
                              hipStream_t stream) {
  (void)in_sizes; (void)n_in; (void)out_size; (void)ws_size;
  const float* x     = (const float*)d_in[0];
  const float* w_qkv = (const float*)d_in[1];
  const float* b_qkv = (const float*)d_in[2];
  const float* w_out = (const float*)d_in[3];
  const float* b_out = (const float*)d_in[4];
  float* out = (float*)d_out;

  char* ws = (char*)d_ws;
  unsigned short* x_bf  = (unsigned short*)(ws);                        // 16 MB (reused for y)
  unsigned short* wqkvT = (unsigned short*)(ws + (size_t)16 * 1048576); // 6 MB
  unsigned short* woutT = (unsigned short*)(ws + (size_t)22 * 1048576); // 2 MB
  unsigned short* qkv   = (unsigned short*)(ws + (size_t)24 * 1048576); // 48 MB -> total 72 MB

  // prep (Q weight columns pre-scaled by ATT_C)
  k_cast_bf16<<<dim3((MM * DD) / (256 * 8)), 256, 0, stream>>>(x, x_bf, MM * DD);
  k_transpose_bf16<<<dim3(3 * DD / 32, DD / 32), 256, 0, stream>>>(w_qkv, wqkvT, DD, 3 * DD,
                                                                   ATT_C, DD);
  k_transpose_bf16<<<dim3(DD / 32, DD / 32), 256, 0, stream>>>(w_out, woutT, DD, DD, 1.f, 0);

  // QKV projection: [8192,3072] bf16
  k_gemm_bt<0><<<dim3(3 * DD / 128, MM / 128), 256, 0, stream>>>(
      x_bf, wqkvT, b_qkv, qkv, MM, 3 * DD, DD, DD);

  // causal attention -> y (bf16, reuses x_bf region)
  k_attn<<<dim3(16, BB * HH), 256, 0, stream>>>(qkv, x_bf);

  // output projection: fp32 out
  k_gemm_bt<1><<<dim3(DD / 128, MM / 128), 256, 0, stream>>>(
      x_bf, woutT, b_out, out, MM, DD, DD, 0);
}

// Round 7
// 191.002 us; speedup vs baseline: 1.2703x; 1.1119x over previous
//
#include <hip/hip_runtime.h>
#include <hip/hip_bf16.h>
#include <cmath>
#include <cstdint>

// Problem dims (fixed by the reference)
#define BB 4
#define SS 2048
#define DD 1024
#define HH 16
#define MM (BB * SS)   // 8192 tokens

// softmax scale folded into Q weight columns: (1/sqrt(64)) * log2(e)
#define ATT_C 0.18033688011112042f

typedef __attribute__((ext_vector_type(8))) __bf16 bf16x8;
typedef __attribute__((ext_vector_type(4))) float f32x4;
typedef __attribute__((ext_vector_type(8))) float f32x8;
typedef __attribute__((ext_vector_type(8))) unsigned short u16x8;
typedef __attribute__((ext_vector_type(2))) unsigned int u32x2;
typedef __attribute__((ext_vector_type(4))) unsigned int u32x4;

typedef const __attribute__((address_space(3))) unsigned short* lds_cp;

__device__ __forceinline__ unsigned short f2bu(float f) {
  __hip_bfloat16 h = __float2bfloat16(f);
  return __builtin_bit_cast(unsigned short, h);
}

__device__ __forceinline__ f32x4 mfma16(bf16x8 a, bf16x8 b, f32x4 c) {
  return __builtin_amdgcn_mfma_f32_16x16x32_bf16(a, b, c, 0, 0, 0);
}

#define GLD16(gp, lp) __builtin_amdgcn_global_load_lds(                     \
    (const __attribute__((address_space(1))) void*)(gp),                    \
    (__attribute__((address_space(3))) void*)(lp), 16, 0, 0)

#define DSR128(dst, ptr, OFFLIT) \
  asm volatile("ds_read_b128 %0, %1 offset:" OFFLIT : "=v"(dst) : "v"(ptr))
#define LGKM(N) do { asm volatile("s_waitcnt lgkmcnt(" #N ")" ::: "memory"); \
                     __builtin_amdgcn_sched_barrier(0); } while (0)
#define VMCNT(N) do { asm volatile("s_waitcnt vmcnt(" #N ")" ::: "memory"); \
                      __builtin_amdgcn_sched_barrier(0); } while (0)

// ---------------- prep: fp32 -> bf16 cast (vectorized) ----------------
__global__ __launch_bounds__(256) void k_cast_bf16(const float* __restrict__ in,
                                                   unsigned short* __restrict__ out,
                                                   int n) {
  int i = (blockIdx.x * 256 + threadIdx.x) * 8;
  if (i >= n) return;
  f32x8 v = *(const f32x8*)(in + i);
  u16x8 o;
#pragma unroll
  for (int j = 0; j < 8; ++j) o[j] = f2bu(v[j]);
  *(u16x8*)(out + i) = o;
}

// ---------------- prep: transpose + cast  in[R][C] f32 -> out[C][R] bf16 ----------------
// output rows < scale_end get multiplied by scale (folds softmax scale into Q weights)
__global__ __launch_bounds__(256) void k_transpose_bf16(const float* __restrict__ in,
                                                        unsigned short* __restrict__ out,
                                                        int R, int C,
                                                        float scale, int scale_end) {
  __shared__ float tile[32][33];
  const int c0 = blockIdx.x * 32, r0 = blockIdx.y * 32;
  const int tx = threadIdx.x & 31, ty = threadIdx.x >> 5;  // ty 0..7
#pragma unroll
  for (int i = ty; i < 32; i += 8)
    tile[i][tx] = in[(size_t)(r0 + i) * C + c0 + tx];
  __syncthreads();
#pragma unroll
  for (int i = ty; i < 32; i += 8) {
    float v = tile[tx][i];
    if (c0 + i < scale_end) v *= scale;
    out[(size_t)(c0 + i) * R + r0 + tx] = f2bu(v);
  }
}

// ---------------- bf16 GEMM: 128x128 tile, 2-deep counted pipeline ----------------
// C[M][N] = A[M][K] * Bt[N][K]^T + bias[N]  (bias cols < bias_scale_end scaled by ATT_C)
// LDS tiles [128 rows][64 k] with 16B-chunk XOR swizzle: LDS(row, ch) holds global
// chunk ch^(row&7); staged via pre-swizzled per-lane global source (linear LDS dest).
// Per K-tile: 16 ds_read_b128 (all frags) -> lgkm(8) -> MFMA kk0 -> lgkm(0)+bar
// (buffer free) -> stage(t+2) -> MFMA kk1 -> vmcnt(8)+bar (t+1 landed). vmcnt never
// drains to 0 in steady state; stage loads span barriers (T4).
template <int OUT_F32>
__global__ __launch_bounds__(256) void k_gemm_bt(const unsigned short* __restrict__ A,
                                                 const unsigned short* __restrict__ Bt,
                                                 const float* __restrict__ bias,
                                                 void* __restrict__ Cout,
                                                 int M, int N, int K, int bias_scale_end) {
  __shared__ __attribute__((aligned(16))) unsigned short lA[2][128 * 64];
  __shared__ __attribute__((aligned(16))) unsigned short lB[2][128 * 64];
  const int tid = threadIdx.x;
  const int wave = tid >> 6, lane = tid & 63;
  const int g = lane >> 4, c = lane & 15;
  const int wr = wave >> 1, wc = wave & 1;
  const int m0 = blockIdx.y * 128, n0 = blockIdx.x * 128;
  const int srow = lane >> 3;                  // 0..7 row within 8-row group
  const int sch  = ((lane & 7) ^ srow) * 8;    // XOR-pre-swizzled source k-chunk

  f32x4 acc[4][4] = {};
  const int nkt = K >> 6;

#define GSTAGE(buf, kt) do {                                                     \
    const int k0s = (kt) * 64;                                                   \
    _Pragma("unroll")                                                            \
    for (int i_ = 0; i_ < 4; ++i_) {                                             \
      const int chunk = i_ * 4 + wave;                                           \
      GLD16(A + (size_t)(m0 + chunk * 8 + srow) * K + k0s + sch,                 \
            &lA[buf][0] + chunk * 512);                                          \
      GLD16(Bt + (size_t)(n0 + chunk * 8 + srow) * K + k0s + sch,                \
            &lB[buf][0] + chunk * 512);                                          \
    }                                                                            \
  } while (0)

  GSTAGE(0, 0);
  GSTAGE(1, 1);
  VMCNT(8);  // tile 0 landed (tile 1's 8 loads still in flight)
  __syncthreads();

  int p = 0;
  for (int kt = 0; kt < nkt; ++kt) {
    // --- all 16 frag reads (kk0 first, then kk1) from buf p ---
    const int x7 = c & 7;
    const lds_cp a0 = (lds_cp)&lA[p][0] + (wr * 64 + c) * 64 + (g ^ x7) * 8;
    const lds_cp b0 = (lds_cp)&lB[p][0] + (wc * 64 + c) * 64 + (g ^ x7) * 8;
    const lds_cp a1 = (lds_cp)&lA[p][0] + (wr * 64 + c) * 64 + ((g ^ x7) ^ 4) * 8;
    const lds_cp b1 = (lds_cp)&lB[p][0] + (wc * 64 + c) * 64 + ((g ^ x7) ^ 4) * 8;
    u32x4 af0[4], bf0[4], af1[4], bf1[4];
    DSR128(af0[0], a0, "0");    DSR128(af0[1], a0, "2048");
    DSR128(af0[2], a0, "4096"); DSR128(af0[3], a0, "6144");
    DSR128(bf0[0], b0, "0");    DSR128(bf0[1], b0, "2048");
    DSR128(bf0[2], b0, "4096"); DSR128(bf0[3], b0, "6144");
    DSR128(af1[0], a1, "0");    DSR128(af1[1], a1, "2048");
    DSR128(af1[2], a1, "4096"); DSR128(af1[3], a1, "6144");
    DSR128(bf1[0], b1, "0");    DSR128(bf1[1], b1, "2048");
    DSR128(bf1[2], b1, "4096"); DSR128(bf1[3], b1, "6144");

    LGKM(8);  // kk0 frags ready (kk1 reads in flight)
    __builtin_amdgcn_s_setprio(1);
#pragma unroll
    for (int mi = 0; mi < 4; ++mi)
#pragma unroll
      for (int ni = 0; ni < 4; ++ni)
        acc[mi][ni] = mfma16(__builtin_bit_cast(bf16x8, af0[mi]),
                             __builtin_bit_cast(bf16x8, bf0[ni]), acc[mi][ni]);
    __builtin_amdgcn_s_setprio(0);

    LGKM(0);          // all reads from buf p done
    __syncthreads();  // every wave consumed buf p -> safe to overwrite
    if (kt + 2 < nkt) GSTAGE(p, kt + 2);

    __builtin_amdgcn_s_setprio(1);
#pragma unroll
    for (int mi = 0; mi < 4; ++mi)
#pragma unroll
      for (int ni = 0; ni < 4; ++ni)
        acc[mi][ni] = mfma16(__builtin_bit_cast(bf16x8, af1[mi]),
                             __builtin_bit_cast(bf16x8, bf1[ni]), acc[mi][ni]);
    __builtin_amdgcn_s_setprio(0);

    if (kt + 2 < nkt) { VMCNT(8); } else { VMCNT(0); }  // tile kt+1 landed
    __syncthreads();
    p ^= 1;
  }
#undef GSTAGE

#pragma unroll
  for (int mi = 0; mi < 4; ++mi)
#pragma unroll
    for (int ni = 0; ni < 4; ++ni) {
      const int col = n0 + wc * 64 + ni * 16 + c;
      float bv = bias[col];
      if (col < bias_scale_end) bv *= ATT_C;
#pragma unroll
      for (int r = 0; r < 4; ++r) {
        const int row = m0 + wr * 64 + mi * 16 + g * 4 + r;
        const float v = acc[mi][ni][r] + bv;
        if (OUT_F32)
          ((float*)Cout)[(size_t)row * N + col] = v;
        else
          ((unsigned short*)Cout)[(size_t)row * N + col] = f2bu(v);
      }
    }
}

// ---------------- causal flash attention (swapped QK^T, tr-read PV) ----------------
// qkv: [B*S][3072] bf16 (Q at 0 pre-scaled by ATT_C, K at 1024, V at 2048; head h at h*64)
// y:   [B*S][1024] bf16
// Block: 4 waves x 16 Q rows = 64-row q-tile; each block runs TWO q-tiles (31-x, x)
// sequentially -> uniform 33 tile-steps. Grid 16x64 = 1024 blocks (~4/CU, 16 waves/CU).
// KVBLK=64, dbuf LDS.
// K LDS: row-major [64 keys][64 hd], 16B-chunk XOR swizzle ch^(row&7); staged coalesced.
// V LDS: tr-subtiles ordered (k4*4+dc)*128B -> staging is 8 contiguous rows per GLD16
//   (coalesced); tr-read uses group-strided base (lane>>4)*512B + (lane&15)*8B.
// Row-sums of P via ones-MFMA (lands in o's register layout; no shfl).
__global__ __launch_bounds__(256) void k_attn(const unsigned short* __restrict__ qkv,
                                              unsigned short* __restrict__ y) {
  __shared__ __attribute__((aligned(16))) unsigned short lK[2][4096];
  __shared__ __attribute__((aligned(16))) unsigned short lV[2][4096];

  const int tid = threadIdx.x, wave = tid >> 6, lane = tid & 63;
  const int g = lane >> 4, c = lane & 15;
  const int bh = blockIdx.y, b = bh >> 4, hc = bh & 15;
  const size_t rb = (size_t)b * SS;

  // staging lane constants
  const int kRow = lane >> 3;                                  // 0..7 row within group
  const int kCh  = ((lane & 7) ^ kRow) * 8;                    // XOR-swizzled dim chunk
  const int vRow = 4 * ((lane >> 5) & 1) + ((lane >> 1) & 3);  // 0..7 key within group
  const int vDim = 16 * ((lane >> 3) & 3) + (lane & 1) * 8;    // dim offset

#define STAGE(buf, kb) do {                                                        \
    const int k0s = (kb) * 64;                                                     \
    const int g16 = wave * 16;                                                     \
    GLD16(qkv + (rb + k0s + g16 + kRow) * 3072 + 1024 + hc * 64 + kCh,             \
          &lK[buf][0] + g16 * 64);                                                 \
    GLD16(qkv + (rb + k0s + g16 + 8 + kRow) * 3072 + 1024 + hc * 64 + kCh,         \
          &lK[buf][0] + (g16 + 8) * 64);                                           \
    GLD16(qkv + (rb + k0s + g16 + vRow) * 3072 + 2048 + hc * 64 + vDim,            \
          &lV[buf][0] + g16 * 64);                                                 \
    GLD16(qkv + (rb + k0s + g16 + 8 + vRow) * 3072 + 2048 + hc * 64 + vDim,        \
          &lV[buf][0] + (g16 + 8) * 64);                                           \
  } while (0)

#define TRRD(dst, OFFLIT) \
  asm volatile("ds_read_b64_tr_b16 %0, %1 offset:" OFFLIT : "=v"(dst) : "v"(vp))

  // all-ones B-frag for row-sum MFMA
  bf16x8 onesf;
  {
    u16x8 t;
#pragma unroll
    for (int j = 0; j < 8; ++j) t[j] = 0x3F80;  // bf16 1.0
    onesf = __builtin_bit_cast(bf16x8, t);
  }

  auto run_qtile = [&](int qt) {
    const int qw = qt * 64 + wave * 16;  // wave's first q row (16 rows per wave)

    // Q B-frags (scale pre-folded into weights): B[col=q=c][k=hd]
    bf16x8 qf[2];
#pragma unroll
    for (int kh = 0; kh < 2; ++kh)
      qf[kh] = *(const bf16x8*)(qkv + (rb + qw + c) * 3072 + hc * 64 + kh * 32 + g * 8);

    float mrun = -INFINITY;
    f32x4 lsum = {};
    f32x4 o[4] = {};
    const int nkb = qt + 1;

    auto compute = [&](int buf, int kb) {
      const int k0 = kb * 64;
      if (k0 > qw + 15) return;  // fully masked for this wave (wave-uniform)

      // --- K fragments: swizzled b128 reads + issue V tr-reads (kh=0) ---
      const lds_cp kbase = (lds_cp)&lK[buf][0];
      const lds_cp kp0 = kbase + c * 64 + ((g ^ (c & 7))) * 8;
      const lds_cp kp1 = kbase + c * 64 + (((4 + g) ^ (c & 7))) * 8;
      u32x4 kr[8];
      DSR128(kr[0], kp0, "0");    DSR128(kr[1], kp0, "2048");
      DSR128(kr[2], kp0, "4096"); DSR128(kr[3], kp0, "6144");
      DSR128(kr[4], kp1, "0");    DSR128(kr[5], kp1, "2048");
      DSR128(kr[6], kp1, "4096"); DSR128(kr[7], kp1, "6144");
      const lds_cp vp = (lds_cp)&lV[buf][0] + (lane >> 4) * 256 + (lane & 15) * 4;
      u32x2 t0[8];  // [2*dc + jh] : subtile (k4 = 4*jh + g, dc)
      TRRD(t0[0], "0");   TRRD(t0[1], "2048");
      TRRD(t0[2], "128"); TRRD(t0[3], "2176");
      TRRD(t0[4], "256"); TRRD(t0[5], "2304");
      TRRD(t0[6], "384"); TRRD(t0[7], "2432");
      LGKM(8);  // kr ready (t0 still in flight)

      // --- S^T = mfma(K, Q): D[key=4g+r (+16kf)][q=c] ---
      f32x4 s[4];
      __builtin_amdgcn_s_setprio(1);
#pragma unroll
      for (int kf = 0; kf < 4; ++kf) {
        const bf16x8 ka = __builtin_bit_cast(bf16x8, kr[kf]);
        const bf16x8 kb2 = __builtin_bit_cast(bf16x8, kr[4 + kf]);
        f32x4 a = {};
        a = mfma16(ka, qf[0], a);
        a = mfma16(kb2, qf[1], a);
        s[kf] = a;
      }
      __builtin_amdgcn_s_setprio(0);

      // --- issue V tr-reads for kh=1 (land under softmax/PV0) ---
      u32x2 t1[8];
      TRRD(t1[0], "4096"); TRRD(t1[1], "6144");
      TRRD(t1[2], "4224"); TRRD(t1[3], "6272");
      TRRD(t1[4], "4352"); TRRD(t1[5], "6400");
      TRRD(t1[6], "4480"); TRRD(t1[7], "6528");

      // --- causal mask (diagonal-touching frags only) ---
#pragma unroll
      for (int kf = 0; kf < 4; ++kf)
        if (k0 + kf * 16 + 15 > qw) {
#pragma unroll
          for (int r = 0; r < 4; ++r)
            if (k0 + kf * 16 + 4 * g + r > qw + c) s[kf][r] = -INFINITY;
        }

      // --- online softmax (log2 domain; max3 trees; defer-max) ---
      {
        float a0 = fmaxf(fmaxf(s[0][0], s[0][1]), s[0][2]);
        float a1 = fmaxf(fmaxf(s[0][3], s[1][0]), s[1][1]);
        float a2 = fmaxf(fmaxf(s[1][2], s[1][3]), s[2][0]);
        float a3 = fmaxf(fmaxf(s[2][1], s[2][2]), s[2][3]);
        float a4 = fmaxf(fmaxf(s[3][0], s[3][1]), s[3][2]);
        float b0 = fmaxf(fmaxf(a0, a1), a2);
        float b1 = fmaxf(fmaxf(a3, a4), s[3][3]);
        float tmax = fmaxf(b0, b1);
        tmax = fmaxf(tmax, __shfl_xor(tmax, 16));
        tmax = fmaxf(tmax, __shfl_xor(tmax, 32));
        const float mold = mrun;
        float mt;
        if (__all(tmax - mold <= 8.f)) {
          mt = mold;
        } else {
          mt = fmaxf(mold, tmax);
          const float alpha = __builtin_amdgcn_exp2f(mold - mt);
          mrun = mt;
#pragma unroll
          for (int r = 0; r < 4; ++r) {
            const float ao = __shfl(alpha, (lane & 48) + ((lane & 48) >> 2) + r);
            lsum[r] *= ao;
#pragma unroll
            for (int dc = 0; dc < 4; ++dc) o[dc][r] *= ao;
          }
        }
#pragma unroll
        for (int kf = 0; kf < 4; ++kf)
#pragma unroll
          for (int r = 0; r < 4; ++r)
            s[kf][r] = __builtin_amdgcn_exp2f(s[kf][r] - mt);
      }

      // --- pack P -> bf16 A-frags ---
      bf16x8 pa[2];
#pragma unroll
      for (int kh = 0; kh < 2; ++kh) {
        u16x8 t;
#pragma unroll
        for (int j = 0; j < 4; ++j) {
          t[j]     = f2bu(s[2 * kh][j]);
          t[4 + j] = f2bu(s[2 * kh + 1][j]);
        }
        pa[kh] = __builtin_bit_cast(bf16x8, t);
      }

      LGKM(8);  // t0 ready (t1 younger, still allowed in flight)
      __builtin_amdgcn_s_setprio(1);
      // row-sums via ones-MFMA (replaces fadd tree + shfls)
      lsum = mfma16(pa[0], onesf, lsum);
      lsum = mfma16(pa[1], onesf, lsum);
#pragma unroll
      for (int dc = 0; dc < 4; ++dc) {
        u32x4 vv = {t0[2 * dc][0], t0[2 * dc][1], t0[2 * dc + 1][0], t0[2 * dc + 1][1]};
        const bf16x8 vf = __builtin_bit_cast(bf16x8, vv);
        o[dc] = mfma16(pa[0], vf, o[dc]);
      }
      __builtin_amdgcn_s_setprio(0);

      LGKM(0);  // t1 ready
      __builtin_amdgcn_s_setprio(1);
#pragma unroll
      for (int dc = 0; dc < 4; ++dc) {
        u32x4 vv = {t1[2 * dc][0], t1[2 * dc][1], t1[2 * dc + 1][0], t1[2 * dc + 1][1]};
        const bf16x8 vf = __builtin_bit_cast(bf16x8, vv);
        o[dc] = mfma16(pa[1], vf, o[dc]);
      }
      __builtin_amdgcn_s_setprio(0);
    };

    __syncthreads();  // LDS handoff from previous q-tile (no-op cost on first)
    STAGE(0, 0);
    asm volatile("s_waitcnt vmcnt(0)" ::: "memory");
    __syncthreads();
    int cur = 0;
    for (int kb = 0; kb < nkb - 1; ++kb) {
      STAGE(cur ^ 1, kb + 1);
      compute(cur, kb);
      asm volatile("s_waitcnt vmcnt(0)" ::: "memory");
      __syncthreads();
      cur ^= 1;
    }
    compute(cur, nkb - 1);

    // epilogue: normalize and store (lsum already in o's layout — no shfl)
#pragma unroll
    for (int r = 0; r < 4; ++r) {
      const float inv = __builtin_amdgcn_rcpf(lsum[r]);
      const int q = qw + 4 * g + r;
#pragma unroll
      for (int dc = 0; dc < 4; ++dc)
        y[(rb + q) * 1024 + hc * 64 + dc * 16 + c] = f2bu(o[dc][r] * inv);
    }
  };

  // paired q-tiles: (31-x) then (x) -> uniform 33 tile-steps per block
  run_qtile(31 - (int)blockIdx.x);
  run_qtile((int)blockIdx.x);
#undef STAGE
#undef TRRD
}

// ---------------- launch ----------------
extern "C" void kernel_launch(void* const* d_in, const int* in_sizes, int n_in,
                              void* d_out, int out_size, void* d_ws, size_t ws_size,
                              hipStream_t stream) {
  (void)in_sizes; (void)n_in; (void)out_size; (void)ws_size;
  const float* x     = (const float*)d_in[0];
  const float* w_qkv = (const float*)d_in[1];
  const float* b_qkv = (const float*)d_in[2];
  const float* w_out = (const float*)d_in[3];
  const float* b_out = (const float*)d_in[4];
  float* out = (float*)d_out;

  char* ws = (char*)d_ws;
  unsigned short* x_bf  = (unsigned short*)(ws);                        // 16 MB (reused for y)
  unsigned short* wqkvT = (unsigned short*)(ws + (size_t)16 * 1048576); // 6 MB
  unsigned short* woutT = (unsigned short*)(ws + (size_t)22 * 1048576); // 2 MB
  unsigned short* qkv   = (unsigned short*)(ws + (size_t)24 * 1048576); // 48 MB -> total 72 MB

  // prep (Q weight columns pre-scaled by ATT_C)
  k_cast_bf16<<<dim3((MM * DD) / (256 * 8)), 256, 0, stream>>>(x, x_bf, MM * DD);
  k_transpose_bf16<<<dim3(3 * DD / 32, DD / 32), 256, 0, stream>>>(w_qkv, wqkvT, DD, 3 * DD,
                                                                   ATT_C, DD);
  k_transpose_bf16<<<dim3(DD / 32, DD / 32), 256, 0, stream>>>(w_out, woutT, DD, DD, 1.f, 0);

  // QKV projection: [8192,3072] bf16
  k_gemm_bt<0><<<dim3(3 * DD / 128, MM / 128), 256, 0, stream>>>(
      x_bf, wqkvT, b_qkv, qkv, MM, 3 * DD, DD, DD);

  // causal attention -> y (bf16, reuses x_bf region)
  k_attn<<<dim3(16, BB * HH), 256, 0, stream>>>(qkv, x_bf);

  // output projection: fp32 out
  k_gemm_bt<1><<<dim3(DD / 128, MM / 128), 256, 0, stream>>>(
      x_bf, woutT, b_out, out, MM, DD, DD, 0);
}

// Round 8
// 178.292 us; speedup vs baseline: 1.3609x; 1.0713x over previous
//
#include <hip/hip_runtime.h>
#include <hip/hip_bf16.h>
#include <cmath>
#include <cstdint>

// Problem dims (fixed by the reference)
#define BB 4
#define SS 2048
#define DD 1024
#define HH 16
#define MM (BB * SS)   // 8192 tokens

// softmax scale folded into Q weight columns: (1/sqrt(64)) * log2(e)
#define ATT_C 0.18033688011112042f

typedef __attribute__((ext_vector_type(8))) __bf16 bf16x8;
typedef __attribute__((ext_vector_type(4))) float f32x4;
typedef __attribute__((ext_vector_type(8))) float f32x8;
typedef __attribute__((ext_vector_type(8))) unsigned short u16x8;
typedef __attribute__((ext_vector_type(2))) unsigned int u32x2;
typedef __attribute__((ext_vector_type(4))) unsigned int u32x4;

typedef const __attribute__((address_space(3))) unsigned short* lds_cp;

__device__ __forceinline__ unsigned short f2bu(float f) {
  __hip_bfloat16 h = __float2bfloat16(f);
  return __builtin_bit_cast(unsigned short, h);
}

__device__ __forceinline__ f32x4 mfma16(bf16x8 a, bf16x8 b, f32x4 c) {
  return __builtin_amdgcn_mfma_f32_16x16x32_bf16(a, b, c, 0, 0, 0);
}

#define GLD16(gp, lp) __builtin_amdgcn_global_load_lds(                     \
    (const __attribute__((address_space(1))) void*)(gp),                    \
    (__attribute__((address_space(3))) void*)(lp), 16, 0, 0)

#define DSR128(dst, ptr, OFFLIT) \
  asm volatile("ds_read_b128 %0, %1 offset:" OFFLIT : "=v"(dst) : "v"(ptr))
#define LGKM(N) do { asm volatile("s_waitcnt lgkmcnt(" #N ")" ::: "memory"); \
                     __builtin_amdgcn_sched_barrier(0); } while (0)
#define VMCNT(N) do { asm volatile("s_waitcnt vmcnt(" #N ")" ::: "memory"); \
                      __builtin_amdgcn_sched_barrier(0); } while (0)

// ---------------- prep: fp32 -> bf16 cast (vectorized) ----------------
__global__ __launch_bounds__(256) void k_cast_bf16(const float* __restrict__ in,
                                                   unsigned short* __restrict__ out,
                                                   int n) {
  int i = (blockIdx.x * 256 + threadIdx.x) * 8;
  if (i >= n) return;
  f32x8 v = *(const f32x8*)(in + i);
  u16x8 o;
#pragma unroll
  for (int j = 0; j < 8; ++j) o[j] = f2bu(v[j]);
  *(u16x8*)(out + i) = o;
}

// ---------------- prep: transpose + cast  in[R][C] f32 -> out[C][R] bf16 ----------------
// output rows < scale_end get multiplied by scale (folds softmax scale into Q weights)
__global__ __launch_bounds__(256) void k_transpose_bf16(const float* __restrict__ in,
                                                        unsigned short* __restrict__ out,
                                                        int R, int C,
                                                        float scale, int scale_end) {
  __shared__ float tile[32][33];
  const int c0 = blockIdx.x * 32, r0 = blockIdx.y * 32;
  const int tx = threadIdx.x & 31, ty = threadIdx.x >> 5;  // ty 0..7
#pragma unroll
  for (int i = ty; i < 32; i += 8)
    tile[i][tx] = in[(size_t)(r0 + i) * C + c0 + tx];
  __syncthreads();
#pragma unroll
  for (int i = ty; i < 32; i += 8) {
    float v = tile[tx][i];
    if (c0 + i < scale_end) v *= scale;
    out[(size_t)(c0 + i) * R + r0 + tx] = f2bu(v);
  }
}

// ---------------- bf16 GEMM: 128x128 tile, 2-deep counted pipeline ----------------
// C[M][N] = A[M][K] * Bt[N][K]^T + bias[N]  (bias cols < bias_scale_end scaled by ATT_C)
// LDS tiles [128 rows][64 k] with 16B-chunk XOR swizzle: LDS(row, ch) holds global
// chunk ch^(row&7); staged via pre-swizzled per-lane global source (linear LDS dest).
// Per K-tile: 16 ds_read_b128 (all frags) -> lgkm(8) -> MFMA kk0 -> lgkm(0)+bar
// (buffer free) -> stage(t+2) -> MFMA kk1 -> vmcnt(8)+bar (t+1 landed). vmcnt never
// drains to 0 in steady state; stage loads span barriers (T4).
template <int OUT_F32>
__global__ __launch_bounds__(256) void k_gemm_bt(const unsigned short* __restrict__ A,
                                                 const unsigned short* __restrict__ Bt,
                                                 const float* __restrict__ bias,
                                                 void* __restrict__ Cout,
                                                 int M, int N, int K, int bias_scale_end) {
  __shared__ __attribute__((aligned(16))) unsigned short lA[2][128 * 64];
  __shared__ __attribute__((aligned(16))) unsigned short lB[2][128 * 64];
  const int tid = threadIdx.x;
  const int wave = tid >> 6, lane = tid & 63;
  const int g = lane >> 4, c = lane & 15;
  const int wr = wave >> 1, wc = wave & 1;
  const int m0 = blockIdx.y * 128, n0 = blockIdx.x * 128;
  const int srow = lane >> 3;                  // 0..7 row within 8-row group
  const int sch  = ((lane & 7) ^ srow) * 8;    // XOR-pre-swizzled source k-chunk

  f32x4 acc[4][4] = {};
  const int nkt = K >> 6;

#define GSTAGE(buf, kt) do {                                                     \
    const int k0s = (kt) * 64;                                                   \
    _Pragma("unroll")                                                            \
    for (int i_ = 0; i_ < 4; ++i_) {                                             \
      const int chunk = i_ * 4 + wave;                                           \
      GLD16(A + (size_t)(m0 + chunk * 8 + srow) * K + k0s + sch,                 \
            &lA[buf][0] + chunk * 512);                                          \
      GLD16(Bt + (size_t)(n0 + chunk * 8 + srow) * K + k0s + sch,                \
            &lB[buf][0] + chunk * 512);                                          \
    }                                                                            \
  } while (0)

  GSTAGE(0, 0);
  GSTAGE(1, 1);
  VMCNT(8);  // tile 0 landed (tile 1's 8 loads still in flight)
  __syncthreads();

  int p = 0;
  for (int kt = 0; kt < nkt; ++kt) {
    // --- all 16 frag reads (kk0 first, then kk1) from buf p ---
    const int x7 = c & 7;
    const lds_cp a0 = (lds_cp)&lA[p][0] + (wr * 64 + c) * 64 + (g ^ x7) * 8;
    const lds_cp b0 = (lds_cp)&lB[p][0] + (wc * 64 + c) * 64 + (g ^ x7) * 8;
    const lds_cp a1 = (lds_cp)&lA[p][0] + (wr * 64 + c) * 64 + ((g ^ x7) ^ 4) * 8;
    const lds_cp b1 = (lds_cp)&lB[p][0] + (wc * 64 + c) * 64 + ((g ^ x7) ^ 4) * 8;
    u32x4 af0[4], bf0[4], af1[4], bf1[4];
    DSR128(af0[0], a0, "0");    DSR128(af0[1], a0, "2048");
    DSR128(af0[2], a0, "4096"); DSR128(af0[3], a0, "6144");
    DSR128(bf0[0], b0, "0");    DSR128(bf0[1], b0, "2048");
    DSR128(bf0[2], b0, "4096"); DSR128(bf0[3], b0, "6144");
    DSR128(af1[0], a1, "0");    DSR128(af1[1], a1, "2048");
    DSR128(af1[2], a1, "4096"); DSR128(af1[3], a1, "6144");
    DSR128(bf1[0], b1, "0");    DSR128(bf1[1], b1, "2048");
    DSR128(bf1[2], b1, "4096"); DSR128(bf1[3], b1, "6144");

    LGKM(8);  // kk0 frags ready (kk1 reads in flight)
    __builtin_amdgcn_s_setprio(1);
#pragma unroll
    for (int mi = 0; mi < 4; ++mi)
#pragma unroll
      for (int ni = 0; ni < 4; ++ni)
        acc[mi][ni] = mfma16(__builtin_bit_cast(bf16x8, af0[mi]),
                             __builtin_bit_cast(bf16x8, bf0[ni]), acc[mi][ni]);
    __builtin_amdgcn_s_setprio(0);

    LGKM(0);          // all reads from buf p done
    __syncthreads();  // every wave consumed buf p -> safe to overwrite
    if (kt + 2 < nkt) GSTAGE(p, kt + 2);

    __builtin_amdgcn_s_setprio(1);
#pragma unroll
    for (int mi = 0; mi < 4; ++mi)
#pragma unroll
      for (int ni = 0; ni < 4; ++ni)
        acc[mi][ni] = mfma16(__builtin_bit_cast(bf16x8, af1[mi]),
                             __builtin_bit_cast(bf16x8, bf1[ni]), acc[mi][ni]);
    __builtin_amdgcn_s_setprio(0);

    if (kt + 2 < nkt) { VMCNT(8); } else { VMCNT(0); }  // tile kt+1 landed
    __syncthreads();
    p ^= 1;
  }
#undef GSTAGE

#pragma unroll
  for (int mi = 0; mi < 4; ++mi)
#pragma unroll
    for (int ni = 0; ni < 4; ++ni) {
      const int col = n0 + wc * 64 + ni * 16 + c;
      float bv = bias[col];
      if (col < bias_scale_end) bv *= ATT_C;
#pragma unroll
      for (int r = 0; r < 4; ++r) {
        const int row = m0 + wr * 64 + mi * 16 + g * 4 + r;
        const float v = acc[mi][ni][r] + bv;
        if (OUT_F32)
          ((float*)Cout)[(size_t)row * N + col] = v;
        else
          ((unsigned short*)Cout)[(size_t)row * N + col] = f2bu(v);
      }
    }
}

// ---------------- causal flash attention (swapped QK^T, tr-read PV) ----------------
// qkv: [B*S][3072] bf16 (Q at 0 pre-scaled by ATT_C, K at 1024, V at 2048; head h at h*64)
// y:   [B*S][1024] bf16
// Block: 4 waves x 16 Q rows = 64-row q-tile; each block runs TWO q-tiles (31-p, p)
// sequentially -> uniform 33 tile-steps. 1-D grid 1024 with XCD-binding decode:
//   xcd = id&7, slot = id>>3, bh = xcd + 8*(slot&7), pair = slot>>3.
// All 16 blocks sharing (b,h) land on one XCD (round-robin dispatch) -> that bh's
// 512KB K/V stream stays L2-resident; 8 bh/XCD = 4MB = exactly one XCD L2.
// KVBLK=64, dbuf LDS.
// K LDS: row-major [64 keys][64 hd], 16B-chunk XOR swizzle ch^(row&7); staged coalesced.
// V LDS: tr-subtiles ordered (k4*4+dc)*128B -> staging is 8 contiguous rows per GLD16
//   (coalesced); tr-read uses group-strided base (lane>>4)*512B + (lane&15)*8B.
// Row-sums of P via ones-MFMA (lands in o's register layout; no shfl).
__global__ __launch_bounds__(256) void k_attn(const unsigned short* __restrict__ qkv,
                                              unsigned short* __restrict__ y) {
  __shared__ __attribute__((aligned(16))) unsigned short lK[2][4096];
  __shared__ __attribute__((aligned(16))) unsigned short lV[2][4096];

  const int tid = threadIdx.x, wave = tid >> 6, lane = tid & 63;
  const int g = lane >> 4, c = lane & 15;
  const int id = (int)blockIdx.x;
  const int xcd = id & 7, slot = id >> 3;
  const int bh = xcd + 8 * (slot & 7);   // bh%8 == xcd -> per-XCD K/V residency
  const int pr = slot >> 3;              // 0..15 pair index
  const int b = bh >> 4, hc = bh & 15;
  const size_t rb = (size_t)b * SS;

  // staging lane constants
  const int kRow = lane >> 3;                                  // 0..7 row within group
  const int kCh  = ((lane & 7) ^ kRow) * 8;                    // XOR-swizzled dim chunk
  const int vRow = 4 * ((lane >> 5) & 1) + ((lane >> 1) & 3);  // 0..7 key within group
  const int vDim = 16 * ((lane >> 3) & 3) + (lane & 1) * 8;    // dim offset

#define STAGE(buf, kb) do {                                                        \
    const int k0s = (kb) * 64;                                                     \
    const int g16 = wave * 16;                                                     \
    GLD16(qkv + (rb + k0s + g16 + kRow) * 3072 + 1024 + hc * 64 + kCh,             \
          &lK[buf][0] + g16 * 64);                                                 \
    GLD16(qkv + (rb + k0s + g16 + 8 + kRow) * 3072 + 1024 + hc * 64 + kCh,         \
          &lK[buf][0] + (g16 + 8) * 64);                                           \
    GLD16(qkv + (rb + k0s + g16 + vRow) * 3072 + 2048 + hc * 64 + vDim,            \
          &lV[buf][0] + g16 * 64);                                                 \
    GLD16(qkv + (rb + k0s + g16 + 8 + vRow) * 3072 + 2048 + hc * 64 + vDim,        \
          &lV[buf][0] + (g16 + 8) * 64);                                           \
  } while (0)

#define TRRD(dst, OFFLIT) \
  asm volatile("ds_read_b64_tr_b16 %0, %1 offset:" OFFLIT : "=v"(dst) : "v"(vp))

  // all-ones B-frag for row-sum MFMA
  bf16x8 onesf;
  {
    u16x8 t;
#pragma unroll
    for (int j = 0; j < 8; ++j) t[j] = 0x3F80;  // bf16 1.0
    onesf = __builtin_bit_cast(bf16x8, t);
  }

  auto run_qtile = [&](int qt) {
    const int qw = qt * 64 + wave * 16;  // wave's first q row (16 rows per wave)

    // Q B-frags (scale pre-folded into weights): B[col=q=c][k=hd]
    bf16x8 qf[2];
#pragma unroll
    for (int kh = 0; kh < 2; ++kh)
      qf[kh] = *(const bf16x8*)(qkv + (rb + qw + c) * 3072 + hc * 64 + kh * 32 + g * 8);

    float mrun = -INFINITY;
    f32x4 lsum = {};
    f32x4 o[4] = {};
    const int nkb = qt + 1;

    auto compute = [&](int buf, int kb) {
      const int k0 = kb * 64;
      if (k0 > qw + 15) return;  // fully masked for this wave (wave-uniform)

      // --- K fragments: swizzled b128 reads + issue V tr-reads (kh=0) ---
      const lds_cp kbase = (lds_cp)&lK[buf][0];
      const lds_cp kp0 = kbase + c * 64 + ((g ^ (c & 7))) * 8;
      const lds_cp kp1 = kbase + c * 64 + (((4 + g) ^ (c & 7))) * 8;
      u32x4 kr[8];
      DSR128(kr[0], kp0, "0");    DSR128(kr[1], kp0, "2048");
      DSR128(kr[2], kp0, "4096"); DSR128(kr[3], kp0, "6144");
      DSR128(kr[4], kp1, "0");    DSR128(kr[5], kp1, "2048");
      DSR128(kr[6], kp1, "4096"); DSR128(kr[7], kp1, "6144");
      const lds_cp vp = (lds_cp)&lV[buf][0] + (lane >> 4) * 256 + (lane & 15) * 4;
      u32x2 t0[8];  // [2*dc + jh] : subtile (k4 = 4*jh + g, dc)
      TRRD(t0[0], "0");   TRRD(t0[1], "2048");
      TRRD(t0[2], "128"); TRRD(t0[3], "2176");
      TRRD(t0[4], "256"); TRRD(t0[5], "2304");
      TRRD(t0[6], "384"); TRRD(t0[7], "2432");
      LGKM(8);  // kr ready (t0 still in flight)

      // --- S^T = mfma(K, Q): D[key=4g+r (+16kf)][q=c] ---
      f32x4 s[4];
      __builtin_amdgcn_s_setprio(1);
#pragma unroll
      for (int kf = 0; kf < 4; ++kf) {
        const bf16x8 ka = __builtin_bit_cast(bf16x8, kr[kf]);
        const bf16x8 kb2 = __builtin_bit_cast(bf16x8, kr[4 + kf]);
        f32x4 a = {};
        a = mfma16(ka, qf[0], a);
        a = mfma16(kb2, qf[1], a);
        s[kf] = a;
      }
      __builtin_amdgcn_s_setprio(0);

      // --- issue V tr-reads for kh=1 (land under softmax/PV0) ---
      u32x2 t1[8];
      TRRD(t1[0], "4096"); TRRD(t1[1], "6144");
      TRRD(t1[2], "4224"); TRRD(t1[3], "6272");
      TRRD(t1[4], "4352"); TRRD(t1[5], "6400");
      TRRD(t1[6], "4480"); TRRD(t1[7], "6528");

      // --- causal mask (diagonal-touching frags only) ---
#pragma unroll
      for (int kf = 0; kf < 4; ++kf)
        if (k0 + kf * 16 + 15 > qw) {
#pragma unroll
          for (int r = 0; r < 4; ++r)
            if (k0 + kf * 16 + 4 * g + r > qw + c) s[kf][r] = -INFINITY;
        }

      // --- online softmax (log2 domain; max3 trees; defer-max) ---
      {
        float a0 = fmaxf(fmaxf(s[0][0], s[0][1]), s[0][2]);
        float a1 = fmaxf(fmaxf(s[0][3], s[1][0]), s[1][1]);
        float a2 = fmaxf(fmaxf(s[1][2], s[1][3]), s[2][0]);
        float a3 = fmaxf(fmaxf(s[2][1], s[2][2]), s[2][3]);
        float a4 = fmaxf(fmaxf(s[3][0], s[3][1]), s[3][2]);
        float b0 = fmaxf(fmaxf(a0, a1), a2);
        float b1 = fmaxf(fmaxf(a3, a4), s[3][3]);
        float tmax = fmaxf(b0, b1);
        tmax = fmaxf(tmax, __shfl_xor(tmax, 16));
        tmax = fmaxf(tmax, __shfl_xor(tmax, 32));
        const float mold = mrun;
        float mt;
        if (__all(tmax - mold <= 8.f)) {
          mt = mold;
        } else {
          mt = fmaxf(mold, tmax);
          const float alpha = __builtin_amdgcn_exp2f(mold - mt);
          mrun = mt;
#pragma unroll
          for (int r = 0; r < 4; ++r) {
            const float ao = __shfl(alpha, (lane & 48) + ((lane & 48) >> 2) + r);
            lsum[r] *= ao;
#pragma unroll
            for (int dc = 0; dc < 4; ++dc) o[dc][r] *= ao;
          }
        }
#pragma unroll
        for (int kf = 0; kf < 4; ++kf)
#pragma unroll
          for (int r = 0; r < 4; ++r)
            s[kf][r] = __builtin_amdgcn_exp2f(s[kf][r] - mt);
      }

      // --- pack P -> bf16 A-frags ---
      bf16x8 pa[2];
#pragma unroll
      for (int kh = 0; kh < 2; ++kh) {
        u16x8 t;
#pragma unroll
        for (int j = 0; j < 4; ++j) {
          t[j]     = f2bu(s[2 * kh][j]);
          t[4 + j] = f2bu(s[2 * kh + 1][j]);
        }
        pa[kh] = __builtin_bit_cast(bf16x8, t);
      }

      LGKM(8);  // t0 ready (t1 younger, still allowed in flight)
      __builtin_amdgcn_s_setprio(1);
      // row-sums via ones-MFMA (replaces fadd tree + shfls)
      lsum = mfma16(pa[0], onesf, lsum);
      lsum = mfma16(pa[1], onesf, lsum);
#pragma unroll
      for (int dc = 0; dc < 4; ++dc) {
        u32x4 vv = {t0[2 * dc][0], t0[2 * dc][1], t0[2 * dc + 1][0], t0[2 * dc + 1][1]};
        const bf16x8 vf = __builtin_bit_cast(bf16x8, vv);
        o[dc] = mfma16(pa[0], vf, o[dc]);
      }
      __builtin_amdgcn_s_setprio(0);

      LGKM(0);  // t1 ready
      __builtin_amdgcn_s_setprio(1);
#pragma unroll
      for (int dc = 0; dc < 4; ++dc) {
        u32x4 vv = {t1[2 * dc][0], t1[2 * dc][1], t1[2 * dc + 1][0], t1[2 * dc + 1][1]};
        const bf16x8 vf = __builtin_bit_cast(bf16x8, vv);
        o[dc] = mfma16(pa[1], vf, o[dc]);
      }
      __builtin_amdgcn_s_setprio(0);
    };

    __syncthreads();  // LDS handoff from previous q-tile (no-op cost on first)
    STAGE(0, 0);
    asm volatile("s_waitcnt vmcnt(0)" ::: "memory");
    __syncthreads();
    int cur = 0;
    for (int kb = 0; kb < nkb - 1; ++kb) {
      STAGE(cur ^ 1, kb + 1);
      compute(cur, kb);
      asm volatile("s_waitcnt vmcnt(0)" ::: "memory");
      __syncthreads();
      cur ^= 1;
    }
    compute(cur, nkb - 1);

    // epilogue: normalize and store (lsum already in o's layout — no shfl)
#pragma unroll
    for (int r = 0; r < 4; ++r) {
      const float inv = __builtin_amdgcn_rcpf(lsum[r]);
      const int q = qw + 4 * g + r;
#pragma unroll
      for (int dc = 0; dc < 4; ++dc)
        y[(rb + q) * 1024 + hc * 64 + dc * 16 + c] = f2bu(o[dc][r] * inv);
    }
  };

  // paired q-tiles: (31-p) then (p) -> uniform 33 tile-steps per block
  run_qtile(31 - pr);
  run_qtile(pr);
#undef STAGE
#undef TRRD
}

// ---------------- launch ----------------
extern "C" void kernel_launch(void* const* d_in, const int* in_sizes, int n_in,
                              void* d_out, int out_size, void* d_ws, size_t ws_size,
                              hipStream_t stream) {
  (void)in_sizes; (void)n_in; (void)out_size; (void)ws_size;
  const float* x     = (const float*)d_in[0];
  const float* w_qkv = (const float*)d_in[1];
  const float* b_qkv = (const float*)d_in[2];
  const float* w_out = (const float*)d_in[3];
  const float* b_out = (const float*)d_in[4];
  float* out = (float*)d_out;

  char* ws = (char*)d_ws;
  unsigned short* x_bf  = (unsigned short*)(ws);                        // 16 MB (reused for y)
  unsigned short* wqkvT = (unsigned short*)(ws + (size_t)16 * 1048576); // 6 MB
  unsigned short* woutT = (unsigned short*)(ws + (size_t)22 * 1048576); // 2 MB
  unsigned short* qkv   = (unsigned short*)(ws + (size_t)24 * 1048576); // 48 MB -> total 72 MB

  // prep (Q weight columns pre-scaled by ATT_C)
  k_cast_bf16<<<dim3((MM * DD) / (256 * 8)), 256, 0, stream>>>(x, x_bf, MM * DD);
  k_transpose_bf16<<<dim3(3 * DD / 32, DD / 32), 256, 0, stream>>>(w_qkv, wqkvT, DD, 3 * DD,
                                                                   ATT_C, DD);
  k_transpose_bf16<<<dim3(DD / 32, DD / 32), 256, 0, stream>>>(w_out, woutT, DD, DD, 1.f, 0);

  // QKV projection: [8192,3072] bf16
  k_gemm_bt<0><<<dim3(3 * DD / 128, MM / 128), 256, 0, stream>>>(
      x_bf, wqkvT, b_qkv, qkv, MM, 3 * DD, DD, DD);

  // causal attention -> y (bf16, reuses x_bf region); 1-D grid, XCD-binding decode
  k_attn<<<dim3(1024), 256, 0, stream>>>(qkv, x_bf);

  // output projection: fp32 out
  k_gemm_bt<1><<<dim3(DD / 128, MM / 128), 256, 0, stream>>>(
      x_bf, woutT, b_out, out, MM, DD, DD, 0);
}

// Round 9
// 173.324 us; speedup vs baseline: 1.3999x; 1.0287x over previous
//
#include <hip/hip_runtime.h>
#include <hip/hip_bf16.h>
#include <cmath>
#include <cstdint>

// Problem dims (fixed by the reference)
#define BB 4
#define SS 2048
#define DD 1024
#define HH 16
#define MM (BB * SS)   // 8192 tokens

// softmax scale folded into Q weight columns: (1/sqrt(64)) * log2(e)
#define ATT_C 0.18033688011112042f

typedef __attribute__((ext_vector_type(8))) __bf16 bf16x8;
typedef __attribute__((ext_vector_type(4))) float f32x4;
typedef __attribute__((ext_vector_type(8))) float f32x8;
typedef __attribute__((ext_vector_type(8))) unsigned short u16x8;
typedef __attribute__((ext_vector_type(2))) unsigned int u32x2;
typedef __attribute__((ext_vector_type(4))) unsigned int u32x4;

typedef const __attribute__((address_space(3))) unsigned short* lds_cp;

__device__ __forceinline__ unsigned short f2bu(float f) {
  __hip_bfloat16 h = __float2bfloat16(f);
  return __builtin_bit_cast(unsigned short, h);
}

__device__ __forceinline__ f32x4 mfma16(bf16x8 a, bf16x8 b, f32x4 c) {
  return __builtin_amdgcn_mfma_f32_16x16x32_bf16(a, b, c, 0, 0, 0);
}

#define GLD16(gp, lp) __builtin_amdgcn_global_load_lds(                     \
    (const __attribute__((address_space(1))) void*)(gp),                    \
    (__attribute__((address_space(3))) void*)(lp), 16, 0, 0)

#define DSR128(dst, ptr, OFFLIT) \
  asm volatile("ds_read_b128 %0, %1 offset:" OFFLIT : "=v"(dst) : "v"(ptr))
#define LGKM(N) do { asm volatile("s_waitcnt lgkmcnt(" #N ")" ::: "memory"); \
                     __builtin_amdgcn_sched_barrier(0); } while (0)
#define VMCNT(N) do { asm volatile("s_waitcnt vmcnt(" #N ")" ::: "memory"); \
                      __builtin_amdgcn_sched_barrier(0); } while (0)

// ---------------- prep: fp32 -> bf16 cast (vectorized) ----------------
__global__ __launch_bounds__(256) void k_cast_bf16(const float* __restrict__ in,
                                                   unsigned short* __restrict__ out,
                                                   int n) {
  int i = (blockIdx.x * 256 + threadIdx.x) * 8;
  if (i >= n) return;
  f32x8 v = *(const f32x8*)(in + i);
  u16x8 o;
#pragma unroll
  for (int j = 0; j < 8; ++j) o[j] = f2bu(v[j]);
  *(u16x8*)(out + i) = o;
}

// ---------------- prep: transpose + cast  in[R][C] f32 -> out[C][R] bf16 ----------------
// output rows < scale_end get multiplied by scale (folds softmax scale into Q weights)
__global__ __launch_bounds__(256) void k_transpose_bf16(const float* __restrict__ in,
                                                        unsigned short* __restrict__ out,
                                                        int R, int C,
                                                        float scale, int scale_end) {
  __shared__ float tile[32][33];
  const int c0 = blockIdx.x * 32, r0 = blockIdx.y * 32;
  const int tx = threadIdx.x & 31, ty = threadIdx.x >> 5;  // ty 0..7
#pragma unroll
  for (int i = ty; i < 32; i += 8)
    tile[i][tx] = in[(size_t)(r0 + i) * C + c0 + tx];
  __syncthreads();
#pragma unroll
  for (int i = ty; i < 32; i += 8) {
    float v = tile[tx][i];
    if (c0 + i < scale_end) v *= scale;
    out[(size_t)(c0 + i) * R + r0 + tx] = f2bu(v);
  }
}

// ---------------- bf16 GEMM: 128x128 tile, 2-deep counted pipeline ----------------
// C[M][N] = A[M][K] * Bt[N][K]^T + bias[N]  (bias cols < bias_scale_end scaled by ATT_C)
// LDS tiles [128 rows][64 k] with 16B-chunk XOR swizzle: LDS(row, ch) holds global
// chunk ch^(row&7); staged via pre-swizzled per-lane global source (linear LDS dest).
// Per K-tile: 16 ds_read_b128 (all frags) -> lgkm(8) -> MFMA kk0 -> lgkm(0)+bar
// (buffer free) -> stage(t+2) -> MFMA kk1 -> vmcnt(8)+bar (t+1 landed). vmcnt never
// drains to 0 in steady state; stage loads span barriers (T4).
template <int OUT_F32>
__global__ __launch_bounds__(256) void k_gemm_bt(const unsigned short* __restrict__ A,
                                                 const unsigned short* __restrict__ Bt,
                                                 const float* __restrict__ bias,
                                                 void* __restrict__ Cout,
                                                 int M, int N, int K, int bias_scale_end) {
  __shared__ __attribute__((aligned(16))) unsigned short lA[2][128 * 64];
  __shared__ __attribute__((aligned(16))) unsigned short lB[2][128 * 64];
  const int tid = threadIdx.x;
  const int wave = tid >> 6, lane = tid & 63;
  const int g = lane >> 4, c = lane & 15;
  const int wr = wave >> 1, wc = wave & 1;
  const int m0 = blockIdx.y * 128, n0 = blockIdx.x * 128;
  const int srow = lane >> 3;                  // 0..7 row within 8-row group
  const int sch  = ((lane & 7) ^ srow) * 8;    // XOR-pre-swizzled source k-chunk

  f32x4 acc[4][4] = {};
  const int nkt = K >> 6;

#define GSTAGE(buf, kt) do {                                                     \
    const int k0s = (kt) * 64;                                                   \
    _Pragma("unroll")                                                            \
    for (int i_ = 0; i_ < 4; ++i_) {                                             \
      const int chunk = i_ * 4 + wave;                                           \
      GLD16(A + (size_t)(m0 + chunk * 8 + srow) * K + k0s + sch,                 \
            &lA[buf][0] + chunk * 512);                                          \
      GLD16(Bt + (size_t)(n0 + chunk * 8 + srow) * K + k0s + sch,                \
            &lB[buf][0] + chunk * 512);                                          \
    }                                                                            \
  } while (0)

  GSTAGE(0, 0);
  GSTAGE(1, 1);
  VMCNT(8);  // tile 0 landed (tile 1's 8 loads still in flight)
  __syncthreads();

  int p = 0;
  for (int kt = 0; kt < nkt; ++kt) {
    // --- all 16 frag reads (kk0 first, then kk1) from buf p ---
    const int x7 = c & 7;
    const lds_cp a0 = (lds_cp)&lA[p][0] + (wr * 64 + c) * 64 + (g ^ x7) * 8;
    const lds_cp b0 = (lds_cp)&lB[p][0] + (wc * 64 + c) * 64 + (g ^ x7) * 8;
    const lds_cp a1 = (lds_cp)&lA[p][0] + (wr * 64 + c) * 64 + ((g ^ x7) ^ 4) * 8;
    const lds_cp b1 = (lds_cp)&lB[p][0] + (wc * 64 + c) * 64 + ((g ^ x7) ^ 4) * 8;
    u32x4 af0[4], bf0[4], af1[4], bf1[4];
    DSR128(af0[0], a0, "0");    DSR128(af0[1], a0, "2048");
    DSR128(af0[2], a0, "4096"); DSR128(af0[3], a0, "6144");
    DSR128(bf0[0], b0, "0");    DSR128(bf0[1], b0, "2048");
    DSR128(bf0[2], b0, "4096"); DSR128(bf0[3], b0, "6144");
    DSR128(af1[0], a1, "0");    DSR128(af1[1], a1, "2048");
    DSR128(af1[2], a1, "4096"); DSR128(af1[3], a1, "6144");
    DSR128(bf1[0], b1, "0");    DSR128(bf1[1], b1, "2048");
    DSR128(bf1[2], b1, "4096"); DSR128(bf1[3], b1, "6144");

    LGKM(8);  // kk0 frags ready (kk1 reads in flight)
    __builtin_amdgcn_s_setprio(1);
#pragma unroll
    for (int mi = 0; mi < 4; ++mi)
#pragma unroll
      for (int ni = 0; ni < 4; ++ni)
        acc[mi][ni] = mfma16(__builtin_bit_cast(bf16x8, af0[mi]),
                             __builtin_bit_cast(bf16x8, bf0[ni]), acc[mi][ni]);
    __builtin_amdgcn_s_setprio(0);

    LGKM(0);          // all reads from buf p done
    __syncthreads();  // every wave consumed buf p -> safe to overwrite
    if (kt + 2 < nkt) GSTAGE(p, kt + 2);

    __builtin_amdgcn_s_setprio(1);
#pragma unroll
    for (int mi = 0; mi < 4; ++mi)
#pragma unroll
      for (int ni = 0; ni < 4; ++ni)
        acc[mi][ni] = mfma16(__builtin_bit_cast(bf16x8, af1[mi]),
                             __builtin_bit_cast(bf16x8, bf1[ni]), acc[mi][ni]);
    __builtin_amdgcn_s_setprio(0);

    if (kt + 2 < nkt) { VMCNT(8); } else { VMCNT(0); }  // tile kt+1 landed
    __syncthreads();
    p ^= 1;
  }
#undef GSTAGE

#pragma unroll
  for (int mi = 0; mi < 4; ++mi)
#pragma unroll
    for (int ni = 0; ni < 4; ++ni) {
      const int col = n0 + wc * 64 + ni * 16 + c;
      float bv = bias[col];
      if (col < bias_scale_end) bv *= ATT_C;
#pragma unroll
      for (int r = 0; r < 4; ++r) {
        const int row = m0 + wr * 64 + mi * 16 + g * 4 + r;
        const float v = acc[mi][ni][r] + bv;
        if (OUT_F32)
          ((float*)Cout)[(size_t)row * N + col] = v;
        else
          ((unsigned short*)Cout)[(size_t)row * N + col] = f2bu(v);
      }
    }
}

// ---------------- causal flash attention (swapped QK^T, tr-read PV) ----------------
// qkv: [B*S][3072] bf16 (Q at 0 pre-scaled by ATT_C, K at 1024, V at 2048; head h at h*64)
// y:   [B*S][1024] bf16
// Block: 4 waves x 32 Q rows (m=2) = 128-row q-tile; TWO q-tiles (15-p, p) per block
// -> uniform 34 tile-steps. Grid 512 = 8 xcd x 8 bh x 8 pairs, XCD-binding decode:
//   xcd = id&7, slot = id>>3, bh = xcd + 8*(slot&7), pr = slot>>3.
// All 8 blocks sharing (b,h) land on one XCD -> 8 bh x 512KB = 4MB L2-resident K/V.
// m=2 amortizes each K-frag read / V tr-read over 2x MFMA work (LDS B/qk: 19.5 -> 9.8).
// KVBLK=64, dbuf LDS (32KB).
// K LDS: row-major [64 keys][64 hd], 16B-chunk XOR swizzle ch^(row&7); staged coalesced.
// V LDS: tr-subtiles ordered (k4*4+dc)*128B (coalesced staging); tr-read base
//   (lane>>4)*512B + (lane&15)*8B. Row-sums of P via ones-MFMA.
__global__ __launch_bounds__(256) void k_attn(const unsigned short* __restrict__ qkv,
                                              unsigned short* __restrict__ y) {
  __shared__ __attribute__((aligned(16))) unsigned short lK[2][4096];
  __shared__ __attribute__((aligned(16))) unsigned short lV[2][4096];

  const int tid = threadIdx.x, wave = tid >> 6, lane = tid & 63;
  const int g = lane >> 4, c = lane & 15;
  const int id = (int)blockIdx.x;
  const int xcd = id & 7, slot = id >> 3;
  const int bh = xcd + 8 * (slot & 7);   // bh%8 == xcd -> per-XCD K/V residency
  const int pr = slot >> 3;              // 0..7 pair index
  const int b = bh >> 4, hc = bh & 15;
  const size_t rb = (size_t)b * SS;

  // staging lane constants
  const int kRow = lane >> 3;                                  // 0..7 row within group
  const int kCh  = ((lane & 7) ^ kRow) * 8;                    // XOR-swizzled dim chunk
  const int vRow = 4 * ((lane >> 5) & 1) + ((lane >> 1) & 3);  // 0..7 key within group
  const int vDim = 16 * ((lane >> 3) & 3) + (lane & 1) * 8;    // dim offset

#define STAGE(buf, kb) do {                                                        \
    const int k0s = (kb) * 64;                                                     \
    const int g16 = wave * 16;                                                     \
    GLD16(qkv + (rb + k0s + g16 + kRow) * 3072 + 1024 + hc * 64 + kCh,             \
          &lK[buf][0] + g16 * 64);                                                 \
    GLD16(qkv + (rb + k0s + g16 + 8 + kRow) * 3072 + 1024 + hc * 64 + kCh,         \
          &lK[buf][0] + (g16 + 8) * 64);                                           \
    GLD16(qkv + (rb + k0s + g16 + vRow) * 3072 + 2048 + hc * 64 + vDim,            \
          &lV[buf][0] + g16 * 64);                                                 \
    GLD16(qkv + (rb + k0s + g16 + 8 + vRow) * 3072 + 2048 + hc * 64 + vDim,        \
          &lV[buf][0] + (g16 + 8) * 64);                                           \
  } while (0)

#define TRRD(dst, OFFLIT) \
  asm volatile("ds_read_b64_tr_b16 %0, %1 offset:" OFFLIT : "=v"(dst) : "v"(vp))

  // all-ones B-frag for row-sum MFMA
  bf16x8 onesf;
  {
    u16x8 t;
#pragma unroll
    for (int j = 0; j < 8; ++j) t[j] = 0x3F80;  // bf16 1.0
    onesf = __builtin_bit_cast(bf16x8, t);
  }

  auto run_qtile = [&](int qt) {
    const int qw = qt * 128 + wave * 32;  // wave's first q row (32 rows per wave)

    // Q B-frags (scale pre-folded into weights): B[col=q=c][k=hd]
    bf16x8 qf[2][2];
#pragma unroll
    for (int m = 0; m < 2; ++m)
#pragma unroll
      for (int kh = 0; kh < 2; ++kh)
        qf[m][kh] = *(const bf16x8*)(qkv + (rb + qw + m * 16 + c) * 3072 + hc * 64 + kh * 32 + g * 8);

    float mrun[2] = {-INFINITY, -INFINITY};
    f32x4 lsum[2] = {};
    f32x4 o[2][4] = {};
    const int nkb = 2 * qt + 2;

    auto compute = [&](int buf, int kb) {
      const int k0 = kb * 64;
      if (k0 > qw + 31) return;  // fully masked for this wave (wave-uniform)

      // --- K fragments: swizzled b128 reads + issue V tr-reads (kh=0) ---
      const lds_cp kbase = (lds_cp)&lK[buf][0];
      const lds_cp kp0 = kbase + c * 64 + ((g ^ (c & 7))) * 8;
      const lds_cp kp1 = kbase + c * 64 + (((4 + g) ^ (c & 7))) * 8;
      u32x4 kr[8];
      DSR128(kr[0], kp0, "0");    DSR128(kr[1], kp0, "2048");
      DSR128(kr[2], kp0, "4096"); DSR128(kr[3], kp0, "6144");
      DSR128(kr[4], kp1, "0");    DSR128(kr[5], kp1, "2048");
      DSR128(kr[6], kp1, "4096"); DSR128(kr[7], kp1, "6144");
      const lds_cp vp = (lds_cp)&lV[buf][0] + (lane >> 4) * 256 + (lane & 15) * 4;
      u32x2 t0[8];  // [2*dc + jh] : subtile (k4 = 4*jh + g, dc)
      TRRD(t0[0], "0");   TRRD(t0[1], "2048");
      TRRD(t0[2], "128"); TRRD(t0[3], "2176");
      TRRD(t0[4], "256"); TRRD(t0[5], "2304");
      TRRD(t0[6], "384"); TRRD(t0[7], "2432");
      LGKM(8);  // kr ready (t0 still in flight)

      // --- S^T = mfma(K, Q): D[key=4g+r (+16kf)][q=c (+16m)] ---
      f32x4 s[2][4];
      __builtin_amdgcn_s_setprio(1);
#pragma unroll
      for (int kf = 0; kf < 4; ++kf) {
        const bf16x8 ka = __builtin_bit_cast(bf16x8, kr[kf]);
        const bf16x8 kb2 = __builtin_bit_cast(bf16x8, kr[4 + kf]);
#pragma unroll
        for (int m = 0; m < 2; ++m) {
          f32x4 a = {};
          a = mfma16(ka, qf[m][0], a);
          a = mfma16(kb2, qf[m][1], a);
          s[m][kf] = a;
        }
      }
      __builtin_amdgcn_s_setprio(0);

      // --- issue V tr-reads for kh=1 (land under softmax/PV0) ---
      u32x2 t1[8];
      TRRD(t1[0], "4096"); TRRD(t1[1], "6144");
      TRRD(t1[2], "4224"); TRRD(t1[3], "6272");
      TRRD(t1[4], "4352"); TRRD(t1[5], "6400");
      TRRD(t1[6], "4480"); TRRD(t1[7], "6528");

      // --- causal mask (diagonal-touching frags only) ---
#pragma unroll
      for (int m = 0; m < 2; ++m)
#pragma unroll
        for (int kf = 0; kf < 4; ++kf)
          if (k0 + kf * 16 + 15 > qw + m * 16) {
#pragma unroll
            for (int r = 0; r < 4; ++r)
              if (k0 + kf * 16 + 4 * g + r > qw + m * 16 + c) s[m][kf][r] = -INFINITY;
          }

      // --- online softmax (log2 domain; max3 trees; defer-max) ---
#pragma unroll
      for (int m = 0; m < 2; ++m) {
        float a0 = fmaxf(fmaxf(s[m][0][0], s[m][0][1]), s[m][0][2]);
        float a1 = fmaxf(fmaxf(s[m][0][3], s[m][1][0]), s[m][1][1]);
        float a2 = fmaxf(fmaxf(s[m][1][2], s[m][1][3]), s[m][2][0]);
        float a3 = fmaxf(fmaxf(s[m][2][1], s[m][2][2]), s[m][2][3]);
        float a4 = fmaxf(fmaxf(s[m][3][0], s[m][3][1]), s[m][3][2]);
        float b0 = fmaxf(fmaxf(a0, a1), a2);
        float b1 = fmaxf(fmaxf(a3, a4), s[m][3][3]);
        float tmax = fmaxf(b0, b1);
        tmax = fmaxf(tmax, __shfl_xor(tmax, 16));
        tmax = fmaxf(tmax, __shfl_xor(tmax, 32));
        const float mold = mrun[m];
        float mt;
        if (__all(tmax - mold <= 8.f)) {
          mt = mold;
        } else {
          mt = fmaxf(mold, tmax);
          const float alpha = __builtin_amdgcn_exp2f(mold - mt);
          mrun[m] = mt;
#pragma unroll
          for (int r = 0; r < 4; ++r) {
            const float ao = __shfl(alpha, (lane & 48) + ((lane & 48) >> 2) + r);
            lsum[m][r] *= ao;
#pragma unroll
            for (int dc = 0; dc < 4; ++dc) o[m][dc][r] *= ao;
          }
        }
#pragma unroll
        for (int kf = 0; kf < 4; ++kf)
#pragma unroll
          for (int r = 0; r < 4; ++r)
            s[m][kf][r] = __builtin_amdgcn_exp2f(s[m][kf][r] - mt);
      }

      // --- pack P -> bf16 A-frags ---
      bf16x8 pa[2][2];
#pragma unroll
      for (int m = 0; m < 2; ++m)
#pragma unroll
        for (int kh = 0; kh < 2; ++kh) {
          u16x8 t;
#pragma unroll
          for (int j = 0; j < 4; ++j) {
            t[j]     = f2bu(s[m][2 * kh][j]);
            t[4 + j] = f2bu(s[m][2 * kh + 1][j]);
          }
          pa[m][kh] = __builtin_bit_cast(bf16x8, t);
        }

      LGKM(8);  // t0 ready (t1 younger, still allowed in flight)
      __builtin_amdgcn_s_setprio(1);
      // row-sums via ones-MFMA (replaces fadd tree + shfls)
#pragma unroll
      for (int m = 0; m < 2; ++m) {
        lsum[m] = mfma16(pa[m][0], onesf, lsum[m]);
        lsum[m] = mfma16(pa[m][1], onesf, lsum[m]);
      }
#pragma unroll
      for (int dc = 0; dc < 4; ++dc) {
        u32x4 vv = {t0[2 * dc][0], t0[2 * dc][1], t0[2 * dc + 1][0], t0[2 * dc + 1][1]};
        const bf16x8 vf = __builtin_bit_cast(bf16x8, vv);
#pragma unroll
        for (int m = 0; m < 2; ++m) o[m][dc] = mfma16(pa[m][0], vf, o[m][dc]);
      }
      __builtin_amdgcn_s_setprio(0);

      LGKM(0);  // t1 ready
      __builtin_amdgcn_s_setprio(1);
#pragma unroll
      for (int dc = 0; dc < 4; ++dc) {
        u32x4 vv = {t1[2 * dc][0], t1[2 * dc][1], t1[2 * dc + 1][0], t1[2 * dc + 1][1]};
        const bf16x8 vf = __builtin_bit_cast(bf16x8, vv);
#pragma unroll
        for (int m = 0; m < 2; ++m) o[m][dc] = mfma16(pa[m][1], vf, o[m][dc]);
      }
      __builtin_amdgcn_s_setprio(0);
    };

    __syncthreads();  // LDS handoff from previous q-tile (no-op cost on first)
    STAGE(0, 0);
    asm volatile("s_waitcnt vmcnt(0)" ::: "memory");
    __syncthreads();
    int cur = 0;
    for (int kb = 0; kb < nkb - 1; ++kb) {
      STAGE(cur ^ 1, kb + 1);
      compute(cur, kb);
      asm volatile("s_waitcnt vmcnt(0)" ::: "memory");
      __syncthreads();
      cur ^= 1;
    }
    compute(cur, nkb - 1);

    // epilogue: normalize and store (lsum already in o's layout — no shfl)
#pragma unroll
    for (int m = 0; m < 2; ++m)
#pragma unroll
      for (int r = 0; r < 4; ++r) {
        const float inv = __builtin_amdgcn_rcpf(lsum[m][r]);
        const int q = qw + m * 16 + 4 * g + r;
#pragma unroll
        for (int dc = 0; dc < 4; ++dc)
          y[(rb + q) * 1024 + hc * 64 + dc * 16 + c] = f2bu(o[m][dc][r] * inv);
      }
  };

  // paired q-tiles: (15-p) then (p) -> uniform 34 tile-steps per block
  run_qtile(15 - pr);
  run_qtile(pr);
#undef STAGE
#undef TRRD
}

// ---------------- launch ----------------
extern "C" void kernel_launch(void* const* d_in, const int* in_sizes, int n_in,
                              void* d_out, int out_size, void* d_ws, size_t ws_size,
                              hipStream_t stream) {
  (void)in_sizes; (void)n_in; (void)out_size; (void)ws_size;
  const float* x     = (const float*)d_in[0];
  const float* w_qkv = (const float*)d_in[1];
  const float* b_qkv = (const float*)d_in[2];
  const float* w_out = (const float*)d_in[3];
  const float* b_out = (const float*)d_in[4];
  float* out = (float*)d_out;

  char* ws = (char*)d_ws;
  unsigned short* x_bf  = (unsigned short*)(ws);                        // 16 MB (reused for y)
  unsigned short* wqkvT = (unsigned short*)(ws + (size_t)16 * 1048576); // 6 MB
  unsigned short* woutT = (unsigned short*)(ws + (size_t)22 * 1048576); // 2 MB
  unsigned short* qkv   = (unsigned short*)(ws + (size_t)24 * 1048576); // 48 MB -> total 72 MB

  // prep (Q weight columns pre-scaled by ATT_C)
  k_cast_bf16<<<dim3((MM * DD) / (256 * 8)), 256, 0, stream>>>(x, x_bf, MM * DD);
  k_transpose_bf16<<<dim3(3 * DD / 32, DD / 32), 256, 0, stream>>>(w_qkv, wqkvT, DD, 3 * DD,
                                                                   ATT_C, DD);
  k_transpose_bf16<<<dim3(DD / 32, DD / 32), 256, 0, stream>>>(w_out, woutT, DD, DD, 1.f, 0);

  // QKV projection: [8192,3072] bf16
  k_gemm_bt<0><<<dim3(3 * DD / 128, MM / 128), 256, 0, stream>>>(
      x_bf, wqkvT, b_qkv, qkv, MM, 3 * DD, DD, DD);

  // causal attention -> y (bf16, reuses x_bf region); grid 512, XCD-binding decode
  k_attn<<<dim3(512), 256, 0, stream>>>(qkv, x_bf);

  // output projection: fp32 out
  k_gemm_bt<1><<<dim3(DD / 128, MM / 128), 256, 0, stream>>>(
      x_bf, woutT, b_out, out, MM, DD, DD, 0);
}